// Round 2
// baseline (412.735 us; speedup 1.0000x reference)
//
#include <hip/hip_runtime.h>
#include <hip/hip_bf16.h>

#define U_CNT 339
#define S_CNT 5825
#define N_CNT 6164          // U + S
#define D_DIM 128
#define R_DIM 32
#define B_CNT 500000
#define M_EDGE 400000       // 2*NNZ (symmetrized)
#define H_DIM 64
#define LN_EPS 1e-5f

// ---- padded dims ----
#define SPAD 5856           // 183*32  (s padded to K-granularity 32)
#define UPAD 352            // 11*32   (u padded)
#define KT_S 183            // s as K: 5856/32
#define KT_U 11             // u as K: 352/32
#define NT_S 365            // s as N: 5840/16 (>= 5825)
#define NT_U 22             // u as N: 352/16

#define ET_U16 (D_DIM * SPAD)          // s-side E^T plane (ushorts)
#define PKS_U16 (KT_U * NT_S * 512)    // B packed [k=u][n=s] MFMA B-frags
#define PKU_U16 (KT_S * NT_U * 512)    // B packed [k=s][n=u] MFMA B-frags
#define BRM_U16 (UPAD * SPAD)          // B row-major [u][s] (MFMA A-operand)
#define WT_U16  (H_DIM * UPAD)         // w^T [j][u] hi/lo planes

// k_heavy role split
#define GU_BLOCKS 121                  // 484 tiles (22x22), 4 waves/block
#define YT_BLOCKS 44                   // 176 tiles (8x22)
#define PC_BLOCK0 (GU_BLOCKS + YT_BLOCKS)   // 165
#define HEAVY_BLOCKS (PC_BLOCK0 + 9)   // 174

// fp32 weight-block offsets (elements)
#define WF_B1   4096
#define WF_G1   4160
#define WF_BE1  4224
#define WF_B2   4288
#define WF_G2   4352
#define WF_BE2  4416
#define WF_W3   4480
#define WF_B3   4544
#define WF_TOT  4545

#define MLP_BLOCKS 1280     // 5 blocks/CU resident (96 VGPR -> 5 waves/SIMD cap)

typedef __hip_bfloat16 bf16;
typedef __attribute__((ext_vector_type(8))) short sh8;   // 8 bf16 (MFMA A/B frag)
typedef __attribute__((ext_vector_type(4))) float f4v;   // MFMA C/D frag

__device__ __forceinline__ float b2f(bf16 x) { return __bfloat162float(x); }
__device__ __forceinline__ unsigned short f2bs(float f) {
    union { bf16 b; unsigned short s; } u;
    u.b = __float2bfloat16(f);
    return u.s;
}
__device__ __forceinline__ float bu2f(unsigned int lo16) {   // bf16 bits -> f32
    return __uint_as_float(lo16 << 16);
}
__device__ __forceinline__ float ldf(const void* p, long i, int isf32) {
    return isf32 ? ((const float*)p)[i] : b2f(((const bf16*)p)[i]);
}

// ---------- dtype detect only ----------
__global__ void k_detect(const void* __restrict__ uE, int* __restrict__ flag) {
    const unsigned short* p = (const unsigned short*)uE;
    unsigned short v = p[2 * threadIdx.x];
    int e = (v >> 7) & 0xFF;
    unsigned long long m = __ballot(e >= 127);
    if (threadIdx.x == 0) flag[0] = (m != 0ull) ? 1 : 0;  // 1 => fp32 buffers
}

// ---------- pre: E_s -> transposed hi/lo planes + edge pack (PkS, PkU, Brm) ----------
__global__ void __launch_bounds__(256)
k_pre(const void* __restrict__ iE,
      unsigned short* __restrict__ EtHi, unsigned short* __restrict__ EtLo,
      const int* __restrict__ rows, const int* __restrict__ cols,
      const void* __restrict__ vals,
      unsigned short* __restrict__ PkS, unsigned short* __restrict__ PkU,
      unsigned short* __restrict__ Brm,
      const int* __restrict__ flag) {
    __shared__ float ls[32 * 129];                    // padded: conflict-free
    int tid = threadIdx.x;
    int isf32 = flag[0];
    if (blockIdx.x < 183) {                           // s-node transpose role
        int sg0 = blockIdx.x * 32;
        int nl = tid >> 3, dbase = (tid & 7) * 16;
        int s = sg0 + nl;
        #pragma unroll
        for (int i = 0; i < 16; ++i) {
            int d = dbase + i;
            float v = (s < S_CNT) ? ldf(iE, (long)s * D_DIM + d, isf32) : 0.f;
            ls[nl * 129 + d] = v;
        }
        __syncthreads();
        int nl2 = tid & 31;
        int s2 = sg0 + nl2;
        #pragma unroll
        for (int i = 0; i < 16; ++i) {
            int d = (tid >> 5) * 16 + i;
            float v = ls[nl2 * 129 + d];
            unsigned short hi = f2bs(v);
            unsigned short lo = f2bs(v - bu2f(hi));
            EtHi[(size_t)d * SPAD + s2] = hi;
            EtLo[(size_t)d * SPAD + s2] = lo;
        }
    }
    // edge packing role (all blocks)
    int e = blockIdx.x * 256 + tid;
    if (e < M_EDGE) {
        int r = rows[e];
        if (r < U_CNT) {
            int u = r, s = cols[e] - U_CNT;
            unsigned short w = f2bs(ldf(vals, e, isf32));
            int kt = u >> 5, kq = (u >> 3) & 3, j = u & 7;
            int nt = s >> 4, nn = s & 15;
            PkS[((kt * NT_S + nt) * 64 + kq * 16 + nn) * 8 + j] = w;
            int kt2 = s >> 5, kq2 = (s >> 3) & 3, j2 = s & 7;
            int nt2 = u >> 4, nn2 = u & 15;
            PkU[((kt2 * NT_U + nt2) * 64 + kq2 * 16 + nn2) * 8 + j2] = w;
            Brm[(size_t)u * SPAD + s] = w;
        }
    }
}

// ---------- heavy: Gu = B*B^T, yT = (B*E_s)^T, Pc/weight prep — one kernel ----------
__global__ void __launch_bounds__(256)
k_heavy(const unsigned short* __restrict__ EtHi, const unsigned short* __restrict__ EtLo,
        const unsigned short* __restrict__ PkU, const unsigned short* __restrict__ Brm,
        float* __restrict__ Gu, float* __restrict__ yT,
        const void* __restrict__ uHy, const void* __restrict__ iHy,
        const void* __restrict__ W1, const void* __restrict__ W2,
        const void* __restrict__ b1, const void* __restrict__ g1,
        const void* __restrict__ be1, const void* __restrict__ b2,
        const void* __restrict__ g2, const void* __restrict__ be2,
        const void* __restrict__ W3, const void* __restrict__ b3,
        float* __restrict__ Pc, float* __restrict__ Wf,
        unsigned short* __restrict__ Wb,
        const int* __restrict__ flag) {
    int tid = threadIdx.x;
    if (blockIdx.x < PC_BLOCK0) {
        int wv = tid >> 6, lane = tid & 63;
        int am = lane & 15, aq = lane >> 4;
        const sh8* Bp = (const sh8*)PkU;
        if (blockIdx.x < GU_BLOCKS) {
            // Gu[u1,u2] = sum_s B[u1,s] * B[u2,s]  (bf16 x bf16, fp32 acc)
            int tile = blockIdx.x * 4 + wv;            // 0..483
            int mt = tile / NT_U, nt = tile % NT_U;
            const unsigned short* arow = Brm + (size_t)(mt * 16 + am) * SPAD;
            f4v acc0 = {0.f, 0.f, 0.f, 0.f}, acc1 = acc0;
            for (int kt = 0; kt < KT_S - 1; kt += 2) {
                sh8 a0 = *(const sh8*)(arow + kt * 32 + aq * 8);
                sh8 bb0 = Bp[(kt * NT_U + nt) * 64 + lane];
                acc0 = __builtin_amdgcn_mfma_f32_16x16x32_bf16(a0, bb0, acc0, 0, 0, 0);
                sh8 a1 = *(const sh8*)(arow + (kt + 1) * 32 + aq * 8);
                sh8 bb1 = Bp[((kt + 1) * NT_U + nt) * 64 + lane];
                acc1 = __builtin_amdgcn_mfma_f32_16x16x32_bf16(a1, bb1, acc1, 0, 0, 0);
            }
            {   // kt = 182 tail
                int kt = KT_S - 1;
                sh8 a0 = *(const sh8*)(arow + kt * 32 + aq * 8);
                sh8 bb0 = Bp[(kt * NT_U + nt) * 64 + lane];
                acc0 = __builtin_amdgcn_mfma_f32_16x16x32_bf16(a0, bb0, acc0, 0, 0, 0);
            }
            #pragma unroll
            for (int reg = 0; reg < 4; ++reg)
                Gu[(size_t)(mt * 16 + aq * 4 + reg) * UPAD + nt * 16 + am]
                    = acc0[reg] + acc1[reg];
        } else {
            // yT[d,u] = sum_s Et[d,s] * B[u,s]   (hi/lo split E, = old u-side hop)
            int tile = (blockIdx.x - GU_BLOCKS) * 4 + wv;   // 0..175
            int mt = tile / NT_U, nt = tile % NT_U;
            const unsigned short* rH = EtHi + (size_t)(mt * 16 + am) * SPAD;
            const unsigned short* rL = EtLo + (size_t)(mt * 16 + am) * SPAD;
            f4v acc0 = {0.f, 0.f, 0.f, 0.f}, acc1 = acc0;
            #pragma unroll 2
            for (int kt = 0; kt < KT_S; ++kt) {
                sh8 bb = Bp[(kt * NT_U + nt) * 64 + lane];
                sh8 ah = *(const sh8*)(rH + kt * 32 + aq * 8);
                sh8 al = *(const sh8*)(rL + kt * 32 + aq * 8);
                acc0 = __builtin_amdgcn_mfma_f32_16x16x32_bf16(ah, bb, acc0, 0, 0, 0);
                acc1 = __builtin_amdgcn_mfma_f32_16x16x32_bf16(al, bb, acc1, 0, 0, 0);
            }
            #pragma unroll
            for (int reg = 0; reg < 4; ++reg)
                yT[(size_t)(mt * 16 + aq * 4 + reg) * UPAD + nt * 16 + am]
                    = acc0[reg] + acc1[reg];
        }
        return;
    }
    // ---- Pc / weight-prep role (blocks 165..173) ----
    int bid = blockIdx.x - PC_BLOCK0;
    int isf32 = flag[0];
    if (bid == 8) {                                   // weight prep
        for (int i = tid; i < 4096; i += 256) {
            int j = i & 7, lane = (i >> 3) & 63, kh = (i >> 9) & 1, t = i >> 10;
            int k = kh * 32 + ((lane >> 4) & 3) * 8 + j;
            int n = t * 16 + (lane & 15);
            Wb[i] = f2bs(ldf(W2, k * 64 + n, isf32));
        }
        for (int i = tid; i < WF_TOT - 4096; i += 256) {
            int g = 4096 + i;
            float v;
            if      (g < WF_G1)  v = ldf(b1,  g - WF_B1,   isf32);
            else if (g < WF_BE1) v = ldf(g1,  g - WF_G1,   isf32);
            else if (g < WF_B2)  v = ldf(be1, g - WF_BE1,  isf32);
            else if (g < WF_G2)  v = ldf(b2,  g - WF_B2,   isf32);
            else if (g < WF_BE2) v = ldf(g2,  g - WF_G2,   isf32);
            else if (g < WF_W3)  v = ldf(be2, g - WF_BE2,  isf32);
            else if (g < WF_B3)  v = ldf(W3,  g - WF_W3,   isf32);
            else                 v = ldf(b3,  0,           isf32);
            Wf[g] = v;
        }
        return;
    }
    int side = bid >> 2;                              // 0 = user, 1 = service
    int j0 = (bid & 3) * 16;                          // 16 Pc-columns per block
    const void* Hy = side ? iHy : uHy;                // [32][128]
    long wbase = (long)side * D_DIM * H_DIM;
    __shared__ float Hs[R_DIM * 129];
    __shared__ float Ws[D_DIM * 16];
    __shared__ float Ts[R_DIM * 16];
    if (isf32) {
        const float* H = (const float*)Hy;
        for (int i = tid; i < R_DIM * D_DIM; i += 256)
            Hs[(i >> 7) * 129 + (i & 127)] = H[i];
        const float* Wp = (const float*)W1 + wbase;
        for (int i = tid; i < D_DIM * 16; i += 256)
            Ws[i] = Wp[(i >> 4) * H_DIM + j0 + (i & 15)];
    } else {
        const unsigned short* H = (const unsigned short*)Hy;
        for (int i = tid; i < R_DIM * D_DIM; i += 256)
            Hs[(i >> 7) * 129 + (i & 127)] = bu2f(H[i]);
        const unsigned short* Wp = (const unsigned short*)W1 + wbase;
        for (int i = tid; i < D_DIM * 16; i += 256)
            Ws[i] = bu2f(Wp[(i >> 4) * H_DIM + j0 + (i & 15)]);
    }
    __syncthreads();
    for (int idx = tid; idx < R_DIM * 16; idx += 256) {
        int a = idx >> 4, j = idx & 15;
        float acc = 0.f;
        #pragma unroll 8
        for (int d = 0; d < D_DIM; ++d)
            acc = fmaf(Hs[a * 129 + d], Ws[d * 16 + j], acc);
        Ts[idx] = acc;
    }
    __syncthreads();
    for (int idx = tid; idx < D_DIM * 16; idx += 256) {
        int d = idx >> 4, j = idx & 15;
        float acc = 0.f;
        #pragma unroll
        for (int a = 0; a < R_DIM; ++a)
            acc = fmaf(Hs[a * 129 + d], Ts[a * 16 + j], acc);
        Pc[side * D_DIM * H_DIM + d * H_DIM + j0 + j] = acc;
    }
}

// ---------- mid: exact fp32 tiny chains, one block per u-row r ----------
// t_e = Gu[r,:]·E_u  (-> w = t_e·Pc_i, split hi/lo, stored transposed)
// t_y = Gu[r,:]·y    (-> A_u[r,:] = t_y·Pc_u + b1)
__global__ void __launch_bounds__(128)
k_mid(const void* __restrict__ uE, const float* __restrict__ Gu,
      const float* __restrict__ yT, const float* __restrict__ Pc,
      const float* __restrict__ Wf,
      unsigned short* __restrict__ wTH, unsigned short* __restrict__ wTL,
      float* __restrict__ A, const int* __restrict__ flag) {
    __shared__ float gr[UPAD];
    __shared__ float te[D_DIM], ty[D_DIM];
    int r = blockIdx.x, tid = threadIdx.x;
    int isf32 = flag[0];
    for (int i = tid; i < U_CNT; i += 128) gr[i] = Gu[(size_t)r * UPAD + i];
    __syncthreads();
    {
        int d = tid;                                  // 0..127
        float se = 0.f, sy = 0.f;
        const float* yrow = yT + (size_t)d * UPAD;
        #pragma unroll 4
        for (int a = 0; a < U_CNT; ++a) {
            float g = gr[a];
            se = fmaf(g, ldf(uE, (long)a * D_DIM + d, isf32), se);
            sy = fmaf(g, yrow[a], sy);
        }
        te[d] = se; ty[d] = sy;
    }
    __syncthreads();
    int j = tid & 63;
    if (tid < 64) {
        float w = 0.f;
        #pragma unroll 8
        for (int d = 0; d < D_DIM; ++d)
            w = fmaf(te[d], Pc[D_DIM * H_DIM + d * H_DIM + j], w);   // Pc_i
        unsigned short hi = f2bs(w);
        unsigned short lo = f2bs(w - bu2f(hi));
        wTH[(size_t)j * UPAD + r] = hi;
        wTL[(size_t)j * UPAD + r] = lo;
    } else {
        float au = Wf[WF_B1 + j];
        #pragma unroll 8
        for (int d = 0; d < D_DIM; ++d)
            au = fmaf(ty[d], Pc[d * H_DIM + j], au);                 // Pc_u
        A[(size_t)r * H_DIM + j] = au;
    }
}

// ---------- A_s = B^T w  via MFMA over PkS; LDS-transposed coalesced store ----------
__global__ void __launch_bounds__(256)
k_As(const unsigned short* __restrict__ wTH, const unsigned short* __restrict__ wTL,
     const unsigned short* __restrict__ PkS, float* __restrict__ A) {
    __shared__ float ls[16][65];
    int nt = blockIdx.x;                              // 0..364
    int tid = threadIdx.x, wv = tid >> 6, lane = tid & 63;
    int am = lane & 15, aq = lane >> 4;
    const sh8* Bp = (const sh8*)PkS;
    const unsigned short* rH = wTH + (size_t)(wv * 16 + am) * UPAD;
    const unsigned short* rL = wTL + (size_t)(wv * 16 + am) * UPAD;
    f4v acc0 = {0.f, 0.f, 0.f, 0.f}, acc1 = acc0;
    #pragma unroll
    for (int kt = 0; kt < KT_U; ++kt) {
        sh8 bb = Bp[(kt * NT_S + nt) * 64 + lane];
        sh8 ah = *(const sh8*)(rH + kt * 32 + aq * 8);
        sh8 al = *(const sh8*)(rL + kt * 32 + aq * 8);
        acc0 = __builtin_amdgcn_mfma_f32_16x16x32_bf16(ah, bb, acc0, 0, 0, 0);
        acc1 = __builtin_amdgcn_mfma_f32_16x16x32_bf16(al, bb, acc1, 0, 0, 0);
    }
    #pragma unroll
    for (int reg = 0; reg < 4; ++reg)
        ls[am][wv * 16 + aq * 4 + reg] = acc0[reg] + acc1[reg];   // [s_local][j]
    __syncthreads();
    int sl = tid >> 4, j0 = (tid & 15) * 4;
    int s = nt * 16 + sl;
    if (s < S_CNT) {
        float4 v = make_float4(ls[sl][j0], ls[sl][j0 + 1], ls[sl][j0 + 2], ls[sl][j0 + 3]);
        *(float4*)(A + (size_t)(U_CNT + s) * H_DIM + j0) = v;
    }
}

// ---------- fused MLP via MFMA: PERSISTENT + SOFTWARE-PIPELINED ----------
// R16-verified body. This round: grid 1024->1280 (96 VGPR allows 5 waves/SIMD;
// 1280 blocks = exactly 5 resident blocks/CU -> +25% latency hiding).
__global__ void __launch_bounds__(256, 5)
HyperModel_65755949301857_kernel(
      const float* __restrict__ A, const int* __restrict__ userIdx,
      const int* __restrict__ servIdx, const float* __restrict__ Wf,
      const unsigned short* __restrict__ Wb,
      void* __restrict__ out, const int* __restrict__ flag) {
    int tid = threadIdx.x;
    int wv = tid >> 6, lane = tid & 63;
    int isf32 = flag[0];
    int m = lane & 15, quad = lane >> 4;

    // hoisted invariants
    const sh8* Bp = (const sh8*)Wb;
    sh8 b00 = Bp[0 * 64 + lane], b01 = Bp[1 * 64 + lane];
    sh8 b10 = Bp[2 * 64 + lane], b11 = Bp[3 * 64 + lane];
    sh8 b20 = Bp[4 * 64 + lane], b21 = Bp[5 * 64 + lane];
    sh8 b30 = Bp[6 * 64 + lane], b31 = Bp[7 * 64 + lane];
    float b2c0 = Wf[WF_B2 + m],      b2c1 = Wf[WF_B2 + 16 + m];
    float b2c2 = Wf[WF_B2 + 32 + m], b2c3 = Wf[WF_B2 + 48 + m];
    float g2c0 = Wf[WF_G2 + m],      g2c1 = Wf[WF_G2 + 16 + m];
    float g2c2 = Wf[WF_G2 + 32 + m], g2c3 = Wf[WF_G2 + 48 + m];
    float e2c0 = Wf[WF_BE2 + m],      e2c1 = Wf[WF_BE2 + 16 + m];
    float e2c2 = Wf[WF_BE2 + 32 + m], e2c3 = Wf[WF_BE2 + 48 + m];
    float w3c0 = Wf[WF_W3 + m],      w3c1 = Wf[WF_W3 + 16 + m];
    float w3c2 = Wf[WF_W3 + 32 + m], w3c3 = Wf[WF_W3 + 48 + m];
    float b3v = Wf[WF_B3];
    const float* G1l = Wf + WF_G1 + quad * 8;
    const float* BE1l = Wf + WF_BE1 + quad * 8;

    const long TILES = B_CNT / 16;                    // 31250
    const long stride = (long)gridDim.x * 4;
    long tile = (long)blockIdx.x * 4 + wv;
    if (tile >= TILES) return;

    // prologue: gather first tile; prefetch idx of second
    int r0 = (int)(tile * 16 + m);
    const float4* Au = (const float4*)(A + (long)userIdx[r0] * 64);
    const float4* As = (const float4*)(A + (long)(servIdx[r0] + U_CNT) * 64);
    float4 bu0 = Au[quad * 2], bu1 = Au[quad * 2 + 1], bu2 = Au[8 + quad * 2], bu3 = Au[9 + quad * 2];
    float4 bs0 = As[quad * 2], bs1 = As[quad * 2 + 1], bs2 = As[8 + quad * 2], bs3 = As[9 + quad * 2];
    long tn = tile + stride;
    int uin = 0, sin = 0;
    if (tn < TILES) {
        int rn = (int)(tn * 16 + m);
        uin = userIdx[rn];
        sin = servIdx[rn] + U_CNT;
    }

    while (true) {
        // combine current buffers into z (frees buf for next prefetch)
        float zl[8], zh[8];
        zl[0] = bu0.x + bs0.x; zl[1] = bu0.y + bs0.y; zl[2] = bu0.z + bs0.z; zl[3] = bu0.w + bs0.w;
        zl[4] = bu1.x + bs1.x; zl[5] = bu1.y + bs1.y; zl[6] = bu1.z + bs1.z; zl[7] = bu1.w + bs1.w;
        zh[0] = bu2.x + bs2.x; zh[1] = bu2.y + bs2.y; zh[2] = bu2.z + bs2.z; zh[3] = bu2.w + bs2.w;
        zh[4] = bu3.x + bs3.x; zh[5] = bu3.y + bs3.y; zh[6] = bu3.z + bs3.z; zh[7] = bu3.w + bs3.w;

        long tcur = tile;
        bool have_next = (tn < TILES);
        if (have_next) {
            // issue next tile's gathers NOW (overlap with compute below)
            const float4* Au2 = (const float4*)(A + (long)uin * 64);
            const float4* As2 = (const float4*)(A + (long)sin * 64);
            bu0 = Au2[quad * 2]; bu1 = Au2[quad * 2 + 1]; bu2 = Au2[8 + quad * 2]; bu3 = Au2[9 + quad * 2];
            bs0 = As2[quad * 2]; bs1 = As2[quad * 2 + 1]; bs2 = As2[8 + quad * 2]; bs3 = As2[9 + quad * 2];
            long tnn = tn + stride;
            if (tnn < TILES) {
                int rnn = (int)(tnn * 16 + m);
                uin = userIdx[rnn];
                sin = servIdx[rnn] + U_CNT;
            }
            tile = tn;
            tn = tnn;
        }

        // ---- compute tile tcur ----
        float s = 0.f, q = 0.f;
        #pragma unroll
        for (int j = 0; j < 8; ++j) {
            s += zl[j] + zh[j];
            q = fmaf(zl[j], zl[j], q);
            q = fmaf(zh[j], zh[j], q);
        }
        s += __shfl_xor(s, 16, 64); s += __shfl_xor(s, 32, 64);
        q += __shfl_xor(q, 16, 64); q += __shfl_xor(q, 32, 64);
        float mu = s * (1.f / 64.f);
        float rs = rsqrtf(q * (1.f / 64.f) - mu * mu + LN_EPS);
        float nm = -mu * rs;

        sh8 a0, a1;
        #pragma unroll
        for (int j = 0; j < 8; ++j) {
            float h0 = fmaxf(fmaf(fmaf(zl[j], rs, nm), G1l[j],      BE1l[j]),      0.f);
            float h1 = fmaxf(fmaf(fmaf(zh[j], rs, nm), G1l[32 + j], BE1l[32 + j]), 0.f);
            a0[j] = (short)f2bs(h0);
            a1[j] = (short)f2bs(h1);
        }

        f4v acc0 = {0.f, 0.f, 0.f, 0.f}, acc1 = acc0, acc2 = acc0, acc3 = acc0;
        acc0 = __builtin_amdgcn_mfma_f32_16x16x32_bf16(a0, b00, acc0, 0, 0, 0);
        acc0 = __builtin_amdgcn_mfma_f32_16x16x32_bf16(a1, b01, acc0, 0, 0, 0);
        acc1 = __builtin_amdgcn_mfma_f32_16x16x32_bf16(a0, b10, acc1, 0, 0, 0);
        acc1 = __builtin_amdgcn_mfma_f32_16x16x32_bf16(a1, b11, acc1, 0, 0, 0);
        acc2 = __builtin_amdgcn_mfma_f32_16x16x32_bf16(a0, b20, acc2, 0, 0, 0);
        acc2 = __builtin_amdgcn_mfma_f32_16x16x32_bf16(a1, b21, acc2, 0, 0, 0);
        acc3 = __builtin_amdgcn_mfma_f32_16x16x32_bf16(a0, b30, acc3, 0, 0, 0);
        acc3 = __builtin_amdgcn_mfma_f32_16x16x32_bf16(a1, b31, acc3, 0, 0, 0);

        float y0[4], y1[4], y2[4], y3[4];
        float srow[4], qrow[4];
        #pragma unroll
        for (int reg = 0; reg < 4; ++reg) {
            y0[reg] = acc0[reg] + b2c0;
            y1[reg] = acc1[reg] + b2c1;
            y2[reg] = acc2[reg] + b2c2;
            y3[reg] = acc3[reg] + b2c3;
            srow[reg] = (y0[reg] + y1[reg]) + (y2[reg] + y3[reg]);
            float qa = y0[reg] * y0[reg];
            qa = fmaf(y1[reg], y1[reg], qa);
            qa = fmaf(y2[reg], y2[reg], qa);
            qa = fmaf(y3[reg], y3[reg], qa);
            qrow[reg] = qa;
        }
        #pragma unroll
        for (int off = 1; off < 16; off <<= 1) {
            #pragma unroll
            for (int reg = 0; reg < 4; ++reg) {
                srow[reg] += __shfl_xor(srow[reg], off, 64);
                qrow[reg] += __shfl_xor(qrow[reg], off, 64);
            }
        }
        float o[4];
        #pragma unroll
        for (int reg = 0; reg < 4; ++reg) {
            float mu2 = srow[reg] * (1.f / 64.f);
            float rs2 = rsqrtf(qrow[reg] * (1.f / 64.f) - mu2 * mu2 + LN_EPS);
            float nm2 = -mu2 * rs2;
            float t0 = fmaxf(fmaf(fmaf(y0[reg], rs2, nm2), g2c0, e2c0), 0.f);
            float t1 = fmaxf(fmaf(fmaf(y1[reg], rs2, nm2), g2c1, e2c1), 0.f);
            float t2 = fmaxf(fmaf(fmaf(y2[reg], rs2, nm2), g2c2, e2c2), 0.f);
            float t3 = fmaxf(fmaf(fmaf(y3[reg], rs2, nm2), g2c3, e2c3), 0.f);
            o[reg] = fmaf(t0, w3c0, fmaf(t1, w3c1, fmaf(t2, w3c2, t3 * w3c3)));
        }
        #pragma unroll
        for (int off = 1; off < 16; off <<= 1) {
            #pragma unroll
            for (int reg = 0; reg < 4; ++reg) o[reg] += __shfl_xor(o[reg], off, 64);
        }
        if (m == 0) {
            long rb = tcur * 16 + quad * 4;
            if (isf32) {
                float4 v = make_float4(o[0] + b3v, o[1] + b3v, o[2] + b3v, o[3] + b3v);
                *(float4*)((float*)out + rb) = v;
            } else {
                ushort4 v;
                v.x = f2bs(o[0] + b3v);
                v.y = f2bs(o[1] + b3v);
                v.z = f2bs(o[2] + b3v);
                v.w = f2bs(o[3] + b3v);
                *(ushort4*)((bf16*)out + rb) = v;
            }
        }
        if (!have_next) break;
    }
}

extern "C" __attribute__((visibility("default")))
void kernel_launch(void* const* d_in, const int* in_sizes, int n_in,
                   void* d_out, int out_size, void* d_ws, size_t ws_size,
                   hipStream_t stream) {
    const void* uE   = d_in[0];
    const void* iE   = d_in[1];
    const void* uHy  = d_in[2];
    const void* iHy  = d_in[3];
    const void* W1   = d_in[4];
    const void* b1   = d_in[5];
    const void* g1   = d_in[6];
    const void* be1  = d_in[7];
    const void* W2   = d_in[8];
    const void* b2   = d_in[9];
    const void* g2   = d_in[10];
    const void* be2  = d_in[11];
    const void* W3   = d_in[12];
    const void* b3   = d_in[13];
    const void* adj_vals = d_in[14];
    const int*  adj_rows = (const int*)d_in[15];
    const int*  adj_cols = (const int*)d_in[16];
    const int*  userIdx  = (const int*)d_in[17];
    const int*  servIdx  = (const int*)d_in[18];

    char* w = (char*)d_ws;
    size_t off = 0;
    auto alloc = [&](size_t bytes) -> char* {
        char* p = w + off;
        off += (bytes + 255) & ~(size_t)255;
        return p;
    };
    unsigned short* EtHi = (unsigned short*)alloc((size_t)ET_U16 * 2);
    unsigned short* EtLo = (unsigned short*)alloc((size_t)ET_U16 * 2);
    float* Gu   = (float*)alloc((size_t)UPAD * UPAD * 4);
    float* yT   = (float*)alloc((size_t)D_DIM * UPAD * 4);
    float* Pc   = (float*)alloc((size_t)2 * D_DIM * H_DIM * 4);
    float* A    = (float*)alloc((size_t)N_CNT * H_DIM * 4);
    float* Wf   = (float*)alloc((size_t)WF_TOT * 4);
    unsigned short* Wb = (unsigned short*)alloc((size_t)4096 * 2);
    int*   flag = (int*)alloc(256);
    // zero-init span: PkS..wTL contiguous (pads must be 0 every iteration)
    unsigned short* PkS = (unsigned short*)alloc((size_t)PKS_U16 * 2);
    unsigned short* PkU = (unsigned short*)alloc((size_t)PKU_U16 * 2);
    unsigned short* Brm = (unsigned short*)alloc((size_t)BRM_U16 * 2);
    unsigned short* wTH = (unsigned short*)alloc((size_t)WT_U16 * 2);
    unsigned short* wTL = (unsigned short*)alloc((size_t)WT_U16 * 2);
    size_t zspan = (size_t)((char*)(wTL + WT_U16) - (char*)PkS);

    k_detect<<<1, 64, 0, stream>>>(uE, flag);
    hipMemsetAsync(PkS, 0, zspan, stream);
    k_pre<<<(M_EDGE + 255) / 256, 256, 0, stream>>>(iE, EtHi, EtLo,
                                                    adj_rows, adj_cols, adj_vals,
                                                    PkS, PkU, Brm, flag);
    k_heavy<<<HEAVY_BLOCKS, 256, 0, stream>>>(EtHi, EtLo, PkU, Brm, Gu, yT,
                                              uHy, iHy, W1, W2, b1, g1, be1,
                                              b2, g2, be2, W3, b3,
                                              Pc, Wf, Wb, flag);
    k_mid<<<U_CNT, 128, 0, stream>>>(uE, Gu, yT, Pc, Wf, wTH, wTL, A, flag);
    k_As<<<NT_S, 256, 0, stream>>>(wTH, wTL, PkS, A);

    HyperModel_65755949301857_kernel<<<MLP_BLOCKS, 256, 0, stream>>>(
        A, userIdx, servIdx, Wf, Wb, d_out, flag);
}

// Round 4
// 231.201 us; speedup vs baseline: 1.7852x; 1.7852x over previous
//
#include <hip/hip_runtime.h>
#include <hip/hip_bf16.h>

#define U_CNT 339
#define S_CNT 5825
#define N_CNT 6164          // U + S
#define D_DIM 128
#define R_DIM 32
#define B_CNT 500000
#define M_EDGE 400000       // 2*NNZ (symmetrized)
#define H_DIM 64
#define LN_EPS 1e-5f

// ---- padded dims ----
#define SPAD 5856           // 183*32  (s padded to K-granularity 32)
#define UPAD 352            // 11*32   (u padded)
#define KT_S 183            // s as K: 5856/32
#define KT_U 11             // u as K: 352/32
#define NT_S 365            // s as N: 5840/16 (>= 5825)
#define NT_U 22             // u as N: 352/16
#define U_KCHUNK 23         // 8*23 = 184 >= 183 (8-way split-K)

#define ET_U16 (D_DIM * SPAD)          // s-side E^T plane (ushorts)
#define PKS_U16 (KT_U * NT_S * 512)    // B packed [k=u][n=s] MFMA B-frags
#define PKU_U16 (KT_S * NT_U * 512)    // B packed [k=s][n=u] MFMA B-frags
#define BRM_U16 (UPAD * SPAD)          // B row-major [u][s] (MFMA A-operand)
#define WT_U16  (H_DIM * UPAD)         // w^T [j][u] hi/lo planes

// k_pre units
#define PRE_TR_UNITS 183
#define PRE_UNITS (PRE_TR_UNITS + (M_EDGE + 255) / 256)   // 1746

// k_heavy roles: 484 GU tiles + 176 yT tiles + 9 Pc/weight blocks, 512 thr
#define HV_GU_END 484
#define HV_YT_END 660
#define HV_BLOCKS 669

// fp32 weight-block offsets (elements)
#define WF_B1   4096
#define WF_G1   4160
#define WF_BE1  4224
#define WF_B2   4288
#define WF_G2   4352
#define WF_BE2  4416
#define WF_W3   4480
#define WF_B3   4544
#define WF_TOT  4545

#define MLP_BLOCKS 1280     // 96 VGPR -> 5 blocks/CU (no min-waves bound: R2 lesson)

typedef __hip_bfloat16 bf16;
typedef __attribute__((ext_vector_type(8))) short sh8;   // 8 bf16 (MFMA A/B frag)
typedef __attribute__((ext_vector_type(4))) float f4v;   // MFMA C/D frag

__device__ __forceinline__ float b2f(bf16 x) { return __bfloat162float(x); }
__device__ __forceinline__ unsigned short f2bs(float f) {
    union { bf16 b; unsigned short s; } u;
    u.b = __float2bfloat16(f);
    return u.s;
}
__device__ __forceinline__ float bu2f(unsigned int lo16) {   // bf16 bits -> f32
    return __uint_as_float(lo16 << 16);
}
__device__ __forceinline__ float ldf(const void* p, long i, int isf32) {
    return isf32 ? ((const float*)p)[i] : b2f(((const bf16*)p)[i]);
}
// per-wave dtype detect (no flag buffer, no extra launch); wave-uniform result
__device__ __forceinline__ int detect_f32(const void* uE) {
    const unsigned short* p = (const unsigned short*)uE;
    int lane = threadIdx.x & 63;
    unsigned short v = p[2 * lane];
    int e = (v >> 7) & 0xFF;
    unsigned long long m = __ballot(e >= 127);
    return (m != 0ull) ? 1 : 0;
}

// ---------- pre: units 0..182 E_s transpose; units 183.. edge pack ----------
__global__ void __launch_bounds__(256)
k_pre(const void* __restrict__ iE,
      unsigned short* __restrict__ EtHi, unsigned short* __restrict__ EtLo,
      const int* __restrict__ rows, const int* __restrict__ cols,
      const void* __restrict__ vals,
      unsigned short* __restrict__ PkS, unsigned short* __restrict__ PkU,
      unsigned short* __restrict__ Brm,
      const void* __restrict__ uE) {
    __shared__ float ls[32 * 129];                    // padded: conflict-free
    int tid = threadIdx.x;
    int isf32 = detect_f32(uE);
    int unit = blockIdx.x;
    if (unit < PRE_TR_UNITS) {                        // s-node transpose role
        int sg0 = unit * 32;
        int nl = tid >> 3, dbase = (tid & 7) * 16;
        int s = sg0 + nl;
        #pragma unroll
        for (int i = 0; i < 16; ++i) {
            int d = dbase + i;
            float v = (s < S_CNT) ? ldf(iE, (long)s * D_DIM + d, isf32) : 0.f;
            ls[nl * 129 + d] = v;
        }
        __syncthreads();
        int nl2 = tid & 31;
        int s2 = sg0 + nl2;
        #pragma unroll
        for (int i = 0; i < 16; ++i) {
            int d = (tid >> 5) * 16 + i;
            float v = ls[nl2 * 129 + d];
            unsigned short hi = f2bs(v);
            unsigned short lo = f2bs(v - bu2f(hi));
            EtHi[(size_t)d * SPAD + s2] = hi;
            EtLo[(size_t)d * SPAD + s2] = lo;
        }
    } else {
        int e = (unit - PRE_TR_UNITS) * 256 + tid;
        if (e < M_EDGE) {
            int r = rows[e];
            if (r < U_CNT) {
                int u = r, s = cols[e] - U_CNT;
                unsigned short w = f2bs(ldf(vals, e, isf32));
                int kt = u >> 5, kq = (u >> 3) & 3, j = u & 7;
                int nt = s >> 4, nn = s & 15;
                PkS[((kt * NT_S + nt) * 64 + kq * 16 + nn) * 8 + j] = w;
                int kt2 = s >> 5, kq2 = (s >> 3) & 3, j2 = s & 7;
                int nt2 = u >> 4, nn2 = u & 15;
                PkU[((kt2 * NT_U + nt2) * 64 + kq2 * 16 + nn2) * 8 + j2] = w;
                Brm[(size_t)u * SPAD + s] = w;
            }
        }
    }
}

// ---------- heavy: 512 threads, 8-way split-K per tile (R0-verified pattern) ----------
// bid<484: Gu tile; bid<660: yT tile; bid 660..668: Pc / weight prep.
__global__ void __launch_bounds__(512)
k_heavy(const unsigned short* __restrict__ EtHi, const unsigned short* __restrict__ EtLo,
        const unsigned short* __restrict__ PkU, const unsigned short* __restrict__ Brm,
        float* __restrict__ Gu, float* __restrict__ yT,
        const void* __restrict__ uHy, const void* __restrict__ iHy,
        const void* __restrict__ W1, const void* __restrict__ W2,
        const void* __restrict__ b1, const void* __restrict__ g1,
        const void* __restrict__ be1, const void* __restrict__ b2,
        const void* __restrict__ g2, const void* __restrict__ be2,
        const void* __restrict__ W3, const void* __restrict__ b3,
        float* __restrict__ Pc, float* __restrict__ Wf,
        unsigned short* __restrict__ Wb,
        const void* __restrict__ uE) {
    __shared__ __align__(16) float sm[6688];          // 26.7 KB arena
    int tid = threadIdx.x;
    int bid = blockIdx.x;
    if (bid < HV_YT_END) {
        int wv = tid >> 6, lane = tid & 63;
        int am = lane & 15, aq = lane >> 4;
        const sh8* Bp = (const sh8*)PkU;
        float4* red = (float4*)sm;                    // [512] float4 = 8 KB
        int k0 = wv * U_KCHUNK, k1 = min(KT_S, k0 + U_KCHUNK);
        f4v acc = {0.f, 0.f, 0.f, 0.f};
        int mt, nt;
        if (bid < HV_GU_END) {
            // Gu[u1,u2] = sum_s B[u1,s]*B[u2,s]
            mt = bid / NT_U; nt = bid % NT_U;
            const unsigned short* arow = Brm + (size_t)(mt * 16 + am) * SPAD;
            for (int kt = k0; kt < k1; ++kt) {
                sh8 a0 = *(const sh8*)(arow + kt * 32 + aq * 8);
                sh8 bb = Bp[(kt * NT_U + nt) * 64 + lane];
                acc = __builtin_amdgcn_mfma_f32_16x16x32_bf16(a0, bb, acc, 0, 0, 0);
            }
        } else {
            // yT[d,u] = sum_s Et[d,s]*B[u,s]  (hi/lo split E)
            int tile = bid - HV_GU_END;
            mt = tile / NT_U; nt = tile % NT_U;
            const unsigned short* rH = EtHi + (size_t)(mt * 16 + am) * SPAD;
            const unsigned short* rL = EtLo + (size_t)(mt * 16 + am) * SPAD;
            for (int kt = k0; kt < k1; ++kt) {
                sh8 bb = Bp[(kt * NT_U + nt) * 64 + lane];
                sh8 ah = *(const sh8*)(rH + kt * 32 + aq * 8);
                sh8 al = *(const sh8*)(rL + kt * 32 + aq * 8);
                acc = __builtin_amdgcn_mfma_f32_16x16x32_bf16(ah, bb, acc, 0, 0, 0);
                acc = __builtin_amdgcn_mfma_f32_16x16x32_bf16(al, bb, acc, 0, 0, 0);
            }
        }
        red[wv * 64 + lane] = make_float4(acc[0], acc[1], acc[2], acc[3]);
        __syncthreads();
        if (wv == 0) {
            float4 v = red[lane];
            #pragma unroll
            for (int w2 = 1; w2 < 8; ++w2) {
                float4 p = red[w2 * 64 + lane];
                v.x += p.x; v.y += p.y; v.z += p.z; v.w += p.w;
            }
            float vr[4] = {v.x, v.y, v.z, v.w};
            float* dst = (bid < HV_GU_END) ? Gu : yT;
            #pragma unroll
            for (int reg = 0; reg < 4; ++reg)
                dst[(size_t)(mt * 16 + aq * 4 + reg) * UPAD + nt * 16 + am] = vr[reg];
        }
        return;
    }
    // ---- Pc / weight-prep roles (512 threads) ----
    int rb = bid - HV_YT_END;                         // 0..8
    int isf32 = detect_f32(uE);
    if (rb == 8) {                                    // weight prep
        for (int i = tid; i < 4096; i += 512) {
            int j = i & 7, lane = (i >> 3) & 63, kh = (i >> 9) & 1, t = i >> 10;
            int k = kh * 32 + ((lane >> 4) & 3) * 8 + j;
            int n = t * 16 + (lane & 15);
            Wb[i] = f2bs(ldf(W2, k * 64 + n, isf32));
        }
        for (int i = tid; i < WF_TOT - 4096; i += 512) {
            int g = 4096 + i;
            float v;
            if      (g < WF_G1)  v = ldf(b1,  g - WF_B1,   isf32);
            else if (g < WF_BE1) v = ldf(g1,  g - WF_G1,   isf32);
            else if (g < WF_B2)  v = ldf(be1, g - WF_BE1,  isf32);
            else if (g < WF_G2)  v = ldf(b2,  g - WF_B2,   isf32);
            else if (g < WF_BE2) v = ldf(g2,  g - WF_G2,   isf32);
            else if (g < WF_W3)  v = ldf(be2, g - WF_BE2,  isf32);
            else if (g < WF_B3)  v = ldf(W3,  g - WF_W3,   isf32);
            else                 v = ldf(b3,  0,           isf32);
            Wf[g] = v;
        }
        return;
    }
    int side = rb >> 2;                               // 0 = user, 1 = service
    int j0 = (rb & 3) * 16;                           // 16 Pc-columns per block
    const void* Hy = side ? iHy : uHy;                // [32][128]
    long wbase = (long)side * D_DIM * H_DIM;
    float* Hs = sm;                                   // [32][129]
    float* Ws = sm + R_DIM * 129;                     // [128][16]
    float* Ts = Ws + D_DIM * 16;                      // [32][16]
    if (isf32) {
        const float* H = (const float*)Hy;
        for (int i = tid; i < R_DIM * D_DIM; i += 512)
            Hs[(i >> 7) * 129 + (i & 127)] = H[i];
        const float* Wp = (const float*)W1 + wbase;
        for (int i = tid; i < D_DIM * 16; i += 512)
            Ws[i] = Wp[(i >> 4) * H_DIM + j0 + (i & 15)];
    } else {
        const unsigned short* H = (const unsigned short*)Hy;
        for (int i = tid; i < R_DIM * D_DIM; i += 512)
            Hs[(i >> 7) * 129 + (i & 127)] = bu2f(H[i]);
        const unsigned short* Wp = (const unsigned short*)W1 + wbase;
        for (int i = tid; i < D_DIM * 16; i += 512)
            Ws[i] = bu2f(Wp[(i >> 4) * H_DIM + j0 + (i & 15)]);
    }
    __syncthreads();
    for (int idx = tid; idx < R_DIM * 16; idx += 512) {
        int a = idx >> 4, j = idx & 15;
        float acc = 0.f;
        #pragma unroll 8
        for (int d = 0; d < D_DIM; ++d)
            acc = fmaf(Hs[a * 129 + d], Ws[d * 16 + j], acc);
        Ts[idx] = acc;
    }
    __syncthreads();
    for (int idx = tid; idx < D_DIM * 16; idx += 512) {
        int d = idx >> 4, j = idx & 15;
        float acc = 0.f;
        #pragma unroll
        for (int a = 0; a < R_DIM; ++a)
            acc = fmaf(Hs[a * 129 + d], Ts[a * 16 + j], acc);
        Pc[side * D_DIM * H_DIM + d * H_DIM + j0 + j] = acc;
    }
}

// ---------- mid: exact fp32 tiny chains, one block per u-row; 256 thr split-a ----------
__global__ void __launch_bounds__(256)
k_mid(const void* __restrict__ uE, const float* __restrict__ Gu,
      const float* __restrict__ yT, const float* __restrict__ Pc,
      const float* __restrict__ Wf,
      unsigned short* __restrict__ wTH, unsigned short* __restrict__ wTL,
      float* __restrict__ A) {
    __shared__ float gr[UPAD];
    __shared__ float te[2 * D_DIM], ty[2 * D_DIM];
    int r = blockIdx.x, tid = threadIdx.x;
    int isf32 = detect_f32(uE);
    for (int i = tid; i < U_CNT; i += 256) gr[i] = Gu[(size_t)r * UPAD + i];
    __syncthreads();
    {
        int d = tid & 127, h = tid >> 7;              // a-loop split in halves
        int a0 = h ? 170 : 0, a1 = h ? U_CNT : 170;
        float se = 0.f, sy = 0.f;
        const float* yrow = yT + (size_t)d * UPAD;
        #pragma unroll 4
        for (int a = a0; a < a1; ++a) {
            float g = gr[a];
            se = fmaf(g, ldf(uE, (long)a * D_DIM + d, isf32), se);
            sy = fmaf(g, yrow[a], sy);
        }
        te[h * 128 + d] = se; ty[h * 128 + d] = sy;
    }
    __syncthreads();
    if (tid < 128) { te[tid] += te[128 + tid]; ty[tid] += ty[128 + tid]; }
    __syncthreads();
    int j = tid & 63;
    if (tid < 64) {
        float w = 0.f;
        #pragma unroll 8
        for (int d = 0; d < D_DIM; ++d)
            w = fmaf(te[d], Pc[D_DIM * H_DIM + d * H_DIM + j], w);   // Pc_i
        unsigned short hi = f2bs(w);
        unsigned short lo = f2bs(w - bu2f(hi));
        wTH[(size_t)j * UPAD + r] = hi;
        wTL[(size_t)j * UPAD + r] = lo;
    } else if (tid < 128) {
        float au = Wf[WF_B1 + j];
        #pragma unroll 8
        for (int d = 0; d < D_DIM; ++d)
            au = fmaf(ty[d], Pc[d * H_DIM + j], au);                 // Pc_u
        A[(size_t)r * H_DIM + j] = au;
    }
}

// ---------- A_s = B^T w via MFMA over PkS; LDS-transposed coalesced store ----------
__global__ void __launch_bounds__(256)
k_as(const unsigned short* __restrict__ wTH, const unsigned short* __restrict__ wTL,
     const unsigned short* __restrict__ PkS, float* __restrict__ A) {
    __shared__ float ls[16][65];
    int nt = blockIdx.x;                              // 0..364
    int tid = threadIdx.x, wv = tid >> 6, lane = tid & 63;
    int am = lane & 15, aq = lane >> 4;
    const sh8* Bp = (const sh8*)PkS;
    const unsigned short* rH = wTH + (size_t)(wv * 16 + am) * UPAD;
    const unsigned short* rL = wTL + (size_t)(wv * 16 + am) * UPAD;
    f4v acc0 = {0.f, 0.f, 0.f, 0.f}, acc1 = acc0;
    #pragma unroll
    for (int kt = 0; kt < KT_U; ++kt) {
        sh8 bb = Bp[(kt * NT_S + nt) * 64 + lane];
        sh8 ah = *(const sh8*)(rH + kt * 32 + aq * 8);
        sh8 al = *(const sh8*)(rL + kt * 32 + aq * 8);
        acc0 = __builtin_amdgcn_mfma_f32_16x16x32_bf16(ah, bb, acc0, 0, 0, 0);
        acc1 = __builtin_amdgcn_mfma_f32_16x16x32_bf16(al, bb, acc1, 0, 0, 0);
    }
    #pragma unroll
    for (int reg = 0; reg < 4; ++reg)
        ls[am][wv * 16 + aq * 4 + reg] = acc0[reg] + acc1[reg];   // [s_local][j]
    __syncthreads();
    int sl = tid >> 4, j0 = (tid & 15) * 4;
    int s = nt * 16 + sl;
    if (s < S_CNT) {
        float4 v = make_float4(ls[sl][j0], ls[sl][j0 + 1], ls[sl][j0 + 2], ls[sl][j0 + 3]);
        *(float4*)(A + (size_t)(U_CNT + s) * H_DIM + j0) = v;
    }
}

// ---------- fused MLP via MFMA: persistent + software-pipelined (R0-verified) ----------
__global__ void __launch_bounds__(256)
HyperModel_65755949301857_kernel(
      const float* __restrict__ A, const int* __restrict__ userIdx,
      const int* __restrict__ servIdx, const float* __restrict__ Wf,
      const unsigned short* __restrict__ Wb,
      void* __restrict__ out, const void* __restrict__ uE) {
    int tid = threadIdx.x;
    int wv = tid >> 6, lane = tid & 63;
    int isf32 = detect_f32(uE);
    int m = lane & 15, quad = lane >> 4;

    const sh8* Bp = (const sh8*)Wb;
    sh8 b00 = Bp[0 * 64 + lane], b01 = Bp[1 * 64 + lane];
    sh8 b10 = Bp[2 * 64 + lane], b11 = Bp[3 * 64 + lane];
    sh8 b20 = Bp[4 * 64 + lane], b21 = Bp[5 * 64 + lane];
    sh8 b30 = Bp[6 * 64 + lane], b31 = Bp[7 * 64 + lane];
    float b2c0 = Wf[WF_B2 + m],      b2c1 = Wf[WF_B2 + 16 + m];
    float b2c2 = Wf[WF_B2 + 32 + m], b2c3 = Wf[WF_B2 + 48 + m];
    float g2c0 = Wf[WF_G2 + m],      g2c1 = Wf[WF_G2 + 16 + m];
    float g2c2 = Wf[WF_G2 + 32 + m], g2c3 = Wf[WF_G2 + 48 + m];
    float e2c0 = Wf[WF_BE2 + m],      e2c1 = Wf[WF_BE2 + 16 + m];
    float e2c2 = Wf[WF_BE2 + 32 + m], e2c3 = Wf[WF_BE2 + 48 + m];
    float w3c0 = Wf[WF_W3 + m],      w3c1 = Wf[WF_W3 + 16 + m];
    float w3c2 = Wf[WF_W3 + 32 + m], w3c3 = Wf[WF_W3 + 48 + m];
    float b3v = Wf[WF_B3];
    const float* G1l = Wf + WF_G1 + quad * 8;
    const float* BE1l = Wf + WF_BE1 + quad * 8;

    const long TILES = B_CNT / 16;                    // 31250
    const long stride = (long)gridDim.x * 4;
    long tile = (long)blockIdx.x * 4 + wv;
    if (tile >= TILES) return;

    int r0 = (int)(tile * 16 + m);
    const float4* Au = (const float4*)(A + (long)userIdx[r0] * 64);
    const float4* As = (const float4*)(A + (long)(servIdx[r0] + U_CNT) * 64);
    float4 bu0 = Au[quad * 2], bu1 = Au[quad * 2 + 1], bu2 = Au[8 + quad * 2], bu3 = Au[9 + quad * 2];
    float4 bs0 = As[quad * 2], bs1 = As[quad * 2 + 1], bs2 = As[8 + quad * 2], bs3 = As[9 + quad * 2];
    long tn = tile + stride;
    int uin = 0, sin = 0;
    if (tn < TILES) {
        int rn = (int)(tn * 16 + m);
        uin = userIdx[rn];
        sin = servIdx[rn] + U_CNT;
    }

    while (true) {
        float zl[8], zh[8];
        zl[0] = bu0.x + bs0.x; zl[1] = bu0.y + bs0.y; zl[2] = bu0.z + bs0.z; zl[3] = bu0.w + bs0.w;
        zl[4] = bu1.x + bs1.x; zl[5] = bu1.y + bs1.y; zl[6] = bu1.z + bs1.z; zl[7] = bu1.w + bs1.w;
        zh[0] = bu2.x + bs2.x; zh[1] = bu2.y + bs2.y; zh[2] = bu2.z + bs2.z; zh[3] = bu2.w + bs2.w;
        zh[4] = bu3.x + bs3.x; zh[5] = bu3.y + bs3.y; zh[6] = bu3.z + bs3.z; zh[7] = bu3.w + bs3.w;

        long tcur = tile;
        bool have_next = (tn < TILES);
        if (have_next) {
            const float4* Au2 = (const float4*)(A + (long)uin * 64);
            const float4* As2 = (const float4*)(A + (long)sin * 64);
            bu0 = Au2[quad * 2]; bu1 = Au2[quad * 2 + 1]; bu2 = Au2[8 + quad * 2]; bu3 = Au2[9 + quad * 2];
            bs0 = As2[quad * 2]; bs1 = As2[quad * 2 + 1]; bs2 = As2[8 + quad * 2]; bs3 = As2[9 + quad * 2];
            long tnn = tn + stride;
            if (tnn < TILES) {
                int rnn = (int)(tnn * 16 + m);
                uin = userIdx[rnn];
                sin = servIdx[rnn] + U_CNT;
            }
            tile = tn;
            tn = tnn;
        }

        float s = 0.f, q = 0.f;
        #pragma unroll
        for (int j = 0; j < 8; ++j) {
            s += zl[j] + zh[j];
            q = fmaf(zl[j], zl[j], q);
            q = fmaf(zh[j], zh[j], q);
        }
        s += __shfl_xor(s, 16, 64); s += __shfl_xor(s, 32, 64);
        q += __shfl_xor(q, 16, 64); q += __shfl_xor(q, 32, 64);
        float mu = s * (1.f / 64.f);
        float rs = rsqrtf(q * (1.f / 64.f) - mu * mu + LN_EPS);
        float nm = -mu * rs;

        sh8 a0, a1;
        #pragma unroll
        for (int j = 0; j < 8; ++j) {
            float h0 = fmaxf(fmaf(fmaf(zl[j], rs, nm), G1l[j],      BE1l[j]),      0.f);
            float h1 = fmaxf(fmaf(fmaf(zh[j], rs, nm), G1l[32 + j], BE1l[32 + j]), 0.f);
            a0[j] = (short)f2bs(h0);
            a1[j] = (short)f2bs(h1);
        }

        f4v acc0 = {0.f, 0.f, 0.f, 0.f}, acc1 = acc0, acc2 = acc0, acc3 = acc0;
        acc0 = __builtin_amdgcn_mfma_f32_16x16x32_bf16(a0, b00, acc0, 0, 0, 0);
        acc0 = __builtin_amdgcn_mfma_f32_16x16x32_bf16(a1, b01, acc0, 0, 0, 0);
        acc1 = __builtin_amdgcn_mfma_f32_16x16x32_bf16(a0, b10, acc1, 0, 0, 0);
        acc1 = __builtin_amdgcn_mfma_f32_16x16x32_bf16(a1, b11, acc1, 0, 0, 0);
        acc2 = __builtin_amdgcn_mfma_f32_16x16x32_bf16(a0, b20, acc2, 0, 0, 0);
        acc2 = __builtin_amdgcn_mfma_f32_16x16x32_bf16(a1, b21, acc2, 0, 0, 0);
        acc3 = __builtin_amdgcn_mfma_f32_16x16x32_bf16(a0, b30, acc3, 0, 0, 0);
        acc3 = __builtin_amdgcn_mfma_f32_16x16x32_bf16(a1, b31, acc3, 0, 0, 0);

        float y0[4], y1[4], y2[4], y3[4];
        float srow[4], qrow[4];
        #pragma unroll
        for (int reg = 0; reg < 4; ++reg) {
            y0[reg] = acc0[reg] + b2c0;
            y1[reg] = acc1[reg] + b2c1;
            y2[reg] = acc2[reg] + b2c2;
            y3[reg] = acc3[reg] + b2c3;
            srow[reg] = (y0[reg] + y1[reg]) + (y2[reg] + y3[reg]);
            float qa = y0[reg] * y0[reg];
            qa = fmaf(y1[reg], y1[reg], qa);
            qa = fmaf(y2[reg], y2[reg], qa);
            qa = fmaf(y3[reg], y3[reg], qa);
            qrow[reg] = qa;
        }
        #pragma unroll
        for (int off = 1; off < 16; off <<= 1) {
            #pragma unroll
            for (int reg = 0; reg < 4; ++reg) {
                srow[reg] += __shfl_xor(srow[reg], off, 64);
                qrow[reg] += __shfl_xor(qrow[reg], off, 64);
            }
        }
        float o[4];
        #pragma unroll
        for (int reg = 0; reg < 4; ++reg) {
            float mu2 = srow[reg] * (1.f / 64.f);
            float rs2 = rsqrtf(qrow[reg] * (1.f / 64.f) - mu2 * mu2 + LN_EPS);
            float nm2 = -mu2 * rs2;
            float t0 = fmaxf(fmaf(fmaf(y0[reg], rs2, nm2), g2c0, e2c0), 0.f);
            float t1 = fmaxf(fmaf(fmaf(y1[reg], rs2, nm2), g2c1, e2c1), 0.f);
            float t2 = fmaxf(fmaf(fmaf(y2[reg], rs2, nm2), g2c2, e2c2), 0.f);
            float t3 = fmaxf(fmaf(fmaf(y3[reg], rs2, nm2), g2c3, e2c3), 0.f);
            o[reg] = fmaf(t0, w3c0, fmaf(t1, w3c1, fmaf(t2, w3c2, t3 * w3c3)));
        }
        #pragma unroll
        for (int off = 1; off < 16; off <<= 1) {
            #pragma unroll
            for (int reg = 0; reg < 4; ++reg) o[reg] += __shfl_xor(o[reg], off, 64);
        }
        if (m == 0) {
            long rb = tcur * 16 + quad * 4;
            if (isf32) {
                float4 v = make_float4(o[0] + b3v, o[1] + b3v, o[2] + b3v, o[3] + b3v);
                *(float4*)((float*)out + rb) = v;
            } else {
                ushort4 v;
                v.x = f2bs(o[0] + b3v);
                v.y = f2bs(o[1] + b3v);
                v.z = f2bs(o[2] + b3v);
                v.w = f2bs(o[3] + b3v);
                *(ushort4*)((bf16*)out + rb) = v;
            }
        }
        if (!have_next) break;
    }
}

extern "C" __attribute__((visibility("default")))
void kernel_launch(void* const* d_in, const int* in_sizes, int n_in,
                   void* d_out, int out_size, void* d_ws, size_t ws_size,
                   hipStream_t stream) {
    const void* uE   = d_in[0];
    const void* iE   = d_in[1];
    const void* uHy  = d_in[2];
    const void* iHy  = d_in[3];
    const void* W1   = d_in[4];
    const void* b1   = d_in[5];
    const void* g1   = d_in[6];
    const void* be1  = d_in[7];
    const void* W2   = d_in[8];
    const void* b2   = d_in[9];
    const void* g2   = d_in[10];
    const void* be2  = d_in[11];
    const void* W3   = d_in[12];
    const void* b3   = d_in[13];
    const void* adj_vals = d_in[14];
    const int*  adj_rows = (const int*)d_in[15];
    const int*  adj_cols = (const int*)d_in[16];
    const int*  userIdx  = (const int*)d_in[17];
    const int*  servIdx  = (const int*)d_in[18];

    char* w = (char*)d_ws;
    size_t off = 0;
    auto alloc = [&](size_t bytes) -> char* {
        char* p = w + off;
        off += (bytes + 255) & ~(size_t)255;
        return p;
    };
    unsigned short* EtHi = (unsigned short*)alloc((size_t)ET_U16 * 2);
    unsigned short* EtLo = (unsigned short*)alloc((size_t)ET_U16 * 2);
    float* Gu   = (float*)alloc((size_t)UPAD * UPAD * 4);
    float* yT   = (float*)alloc((size_t)D_DIM * UPAD * 4);
    float* Pc   = (float*)alloc((size_t)2 * D_DIM * H_DIM * 4);
    float* A    = (float*)alloc((size_t)N_CNT * H_DIM * 4);
    float* Wf   = (float*)alloc((size_t)WF_TOT * 4);
    unsigned short* Wb = (unsigned short*)alloc((size_t)4096 * 2);
    // zero-init span: PkS..wTL contiguous (pads must be 0 every iteration)
    unsigned short* PkS = (unsigned short*)alloc((size_t)PKS_U16 * 2);
    unsigned short* PkU = (unsigned short*)alloc((size_t)PKU_U16 * 2);
    unsigned short* Brm = (unsigned short*)alloc((size_t)BRM_U16 * 2);
    unsigned short* wTH = (unsigned short*)alloc((size_t)WT_U16 * 2);
    unsigned short* wTL = (unsigned short*)alloc((size_t)WT_U16 * 2);
    size_t zspan = (size_t)((char*)(wTL + WT_U16) - (char*)PkS);

    hipMemsetAsync(PkS, 0, zspan, stream);
    k_pre<<<PRE_UNITS, 256, 0, stream>>>(iE, EtHi, EtLo, adj_rows, adj_cols,
                                         adj_vals, PkS, PkU, Brm, uE);
    k_heavy<<<HV_BLOCKS, 512, 0, stream>>>(EtHi, EtLo, PkU, Brm, Gu, yT,
                                           uHy, iHy, W1, W2, b1, g1, be1,
                                           b2, g2, be2, W3, b3,
                                           Pc, Wf, Wb, uE);
    k_mid<<<U_CNT, 256, 0, stream>>>(uE, Gu, yT, Pc, Wf, wTH, wTL, A);
    k_as<<<NT_S, 256, 0, stream>>>(wTH, wTL, PkS, A);
    HyperModel_65755949301857_kernel<<<MLP_BLOCKS, 256, 0, stream>>>(
        A, userIdx, servIdx, Wf, Wb, d_out, uE);
}

// Round 5
// 210.796 us; speedup vs baseline: 1.9580x; 1.0968x over previous
//
#include <hip/hip_runtime.h>
#include <hip/hip_bf16.h>

#define U_CNT 339
#define S_CNT 5825
#define N_CNT 6164          // U + S
#define D_DIM 128
#define R_DIM 32
#define B_CNT 500000
#define NNZ_U 200000        // edges with u-row (first half of rows=concat(u,s))
#define H_DIM 64
#define LN_EPS 1e-5f

// ---- padded dims ----
#define SPAD 5856           // 183*32  (s padded to K-granularity 32)
#define UPAD 352            // 11*32   (u padded)
#define KT_S 183            // s as K: 5856/32
#define KT_U 11             // u as K: 352/32
#define NT_S 365            // s as N: 5840/16 (>= 5825)
#define NT_U 22             // u as N: 352/16
#define U_KCHUNK 23         // 8*23 = 184 >= 183 (8-way split-K)

#define ET_U16 (D_DIM * SPAD)          // s-side E^T plane (ushorts)
#define PKS_U16 (KT_U * NT_S * 512)    // B packed [k=u][n=s] MFMA B-frags
#define PKU_U16 (KT_S * NT_U * 512)    // B packed [k=s][n=u] MFMA B-frags
                                       // (also serves as GU's A-frag: same lane layout)
#define WT_U16  (H_DIM * UPAD)         // w^T [j][u] hi/lo planes

// k_pre units: 183 s-transpose + 11 u-transpose + 782 edge-pack
#define PRE_S_UNITS 183
#define PRE_U_UNITS 11
#define PRE_UT_END (PRE_S_UNITS + PRE_U_UNITS)            // 194
#define PRE_EDGE_UNITS ((NNZ_U + 255) / 256)              // 782
#define PRE_UNITS (PRE_UT_END + PRE_EDGE_UNITS)           // 976

// k_heavy roles: 484 GU tiles + 176 yT tiles + 9 Pc/weight blocks, 512 thr
#define HV_GU_END 484
#define HV_YT_END 660
#define HV_BLOCKS 669

// fp32 weight-block offsets (elements)
#define WF_B1   4096
#define WF_G1   4160
#define WF_BE1  4224
#define WF_B2   4288
#define WF_G2   4352
#define WF_BE2  4416
#define WF_W3   4480
#define WF_B3   4544
#define WF_TOT  4545

#define MLP_BLOCKS 1024     // measured faster than 1280 (R0 51.2us vs R4 58.6us)

typedef __hip_bfloat16 bf16;
typedef __attribute__((ext_vector_type(8))) short sh8;   // 8 bf16 (MFMA A/B frag)
typedef __attribute__((ext_vector_type(4))) float f4v;   // MFMA C/D frag

__device__ __forceinline__ float b2f(bf16 x) { return __bfloat162float(x); }
__device__ __forceinline__ unsigned short f2bs(float f) {
    union { bf16 b; unsigned short s; } u;
    u.b = __float2bfloat16(f);
    return u.s;
}
__device__ __forceinline__ float bu2f(unsigned int lo16) {   // bf16 bits -> f32
    return __uint_as_float(lo16 << 16);
}
__device__ __forceinline__ float ldf(const void* p, long i, int isf32) {
    return isf32 ? ((const float*)p)[i] : b2f(((const bf16*)p)[i]);
}
// per-wave dtype detect (no flag buffer, no extra launch); wave-uniform result
__device__ __forceinline__ int detect_f32(const void* uE) {
    const unsigned short* p = (const unsigned short*)uE;
    int lane = threadIdx.x & 63;
    unsigned short v = p[2 * lane];
    int e = (v >> 7) & 0xFF;
    unsigned long long m = __ballot(e >= 127);
    return (m != 0ull) ? 1 : 0;
}

// ---- DPP within-16-lane sum reduction (pure VALU, no LDS pipe) ----
// R4 post-mortem: 52 __shfl_xor (ds_bpermute) per MLP tile oversubscribed the
// CU LDS pipe (VALUBusy 30%, more blocks made it slower). xor1/xor2 via
// quad_perm, then row_ror:4 + row_ror:8 complete the 16-lane sum.
template<int CTRL>
__device__ __forceinline__ float dpp_add(float x) {
    int t = __builtin_amdgcn_update_dpp(0, __float_as_int(x), CTRL, 0xF, 0xF, false);
    return x + __int_as_float(t);
}
__device__ __forceinline__ float rowsum16(float x) {
    x = dpp_add<0xB1>(x);    // quad_perm [1,0,3,2]  (xor 1)
    x = dpp_add<0x4E>(x);    // quad_perm [2,3,0,1]  (xor 2)
    x = dpp_add<0x124>(x);   // row_ror:4
    x = dpp_add<0x128>(x);   // row_ror:8
    return x;
}

// ---------- pre: s-transpose | u-transpose (f32) | edge pack ----------
__global__ void __launch_bounds__(256)
k_pre(const void* __restrict__ iE,
      unsigned short* __restrict__ EtHi, unsigned short* __restrict__ EtLo,
      const int* __restrict__ rows, const int* __restrict__ cols,
      const void* __restrict__ vals,
      unsigned short* __restrict__ PkS, unsigned short* __restrict__ PkU,
      float* __restrict__ uEt,
      const void* __restrict__ uE) {
    __shared__ float ls[32 * 129];                    // padded: conflict-free
    int tid = threadIdx.x;
    int isf32 = detect_f32(uE);
    int unit = blockIdx.x;
    if (unit < PRE_S_UNITS) {                         // s-node transpose role
        int sg0 = unit * 32;
        int nl = tid >> 3, dbase = (tid & 7) * 16;
        int s = sg0 + nl;
        #pragma unroll
        for (int i = 0; i < 16; ++i) {
            int d = dbase + i;
            float v = (s < S_CNT) ? ldf(iE, (long)s * D_DIM + d, isf32) : 0.f;
            ls[nl * 129 + d] = v;
        }
        __syncthreads();
        int nl2 = tid & 31;
        int s2 = sg0 + nl2;
        #pragma unroll
        for (int i = 0; i < 16; ++i) {
            int d = (tid >> 5) * 16 + i;
            float v = ls[nl2 * 129 + d];
            unsigned short hi = f2bs(v);
            unsigned short lo = f2bs(v - bu2f(hi));
            EtHi[(size_t)d * SPAD + s2] = hi;
            EtLo[(size_t)d * SPAD + s2] = lo;
        }
    } else if (unit < PRE_UT_END) {                   // u-node transpose (f32 out)
        int ug0 = (unit - PRE_S_UNITS) * 32;
        int nl = tid >> 3, dbase = (tid & 7) * 16;
        int u = ug0 + nl;
        #pragma unroll
        for (int i = 0; i < 16; ++i) {
            int d = dbase + i;
            float v = (u < U_CNT) ? ldf(uE, (long)u * D_DIM + d, isf32) : 0.f;
            ls[nl * 129 + d] = v;
        }
        __syncthreads();
        int nl2 = tid & 31;
        int u2 = ug0 + nl2;
        if (u2 < U_CNT) {
            #pragma unroll
            for (int i = 0; i < 16; ++i) {
                int d = (tid >> 5) * 16 + i;
                uEt[(size_t)d * UPAD + u2] = ls[nl2 * 129 + d];
            }
        }
    } else {                                          // edge pack (u-rows only)
        int e = (unit - PRE_UT_END) * 256 + tid;
        if (e < NNZ_U) {
            int r = rows[e];
            if (r < U_CNT) {
                int u = r, s = cols[e] - U_CNT;
                unsigned short w = f2bs(ldf(vals, e, isf32));
                int kt = u >> 5, kq = (u >> 3) & 3, j = u & 7;
                int nt = s >> 4, nn = s & 15;
                PkS[((kt * NT_S + nt) * 64 + kq * 16 + nn) * 8 + j] = w;
                int kt2 = s >> 5, kq2 = (s >> 3) & 3, j2 = s & 7;
                int nt2 = u >> 4, nn2 = u & 15;
                PkU[((kt2 * NT_U + nt2) * 64 + kq2 * 16 + nn2) * 8 + j2] = w;
            }
        }
    }
}

// ---------- heavy: 512 threads, 8-way split-K per tile ----------
// bid<484: Gu tile (A-frag AND B-frag both from PkU -- same lane layout,
// R4 post-mortem algebra: A[m][k]=Badj[mt*16+m][s=k] == PkU frag (kt,mt));
// bid<660: yT tile; bid 660..668: Pc / weight prep.
__global__ void __launch_bounds__(512)
k_heavy(const unsigned short* __restrict__ EtHi, const unsigned short* __restrict__ EtLo,
        const unsigned short* __restrict__ PkU,
        float* __restrict__ Gu, float* __restrict__ yT,
        const void* __restrict__ uHy, const void* __restrict__ iHy,
        const void* __restrict__ W1, const void* __restrict__ W2,
        const void* __restrict__ b1, const void* __restrict__ g1,
        const void* __restrict__ be1, const void* __restrict__ b2,
        const void* __restrict__ g2, const void* __restrict__ be2,
        const void* __restrict__ W3, const void* __restrict__ b3,
        float* __restrict__ Pc, float* __restrict__ Wf,
        unsigned short* __restrict__ Wb,
        const void* __restrict__ uE) {
    __shared__ __align__(16) float sm[6688];          // 26.7 KB arena
    int tid = threadIdx.x;
    int bid = blockIdx.x;
    if (bid < HV_YT_END) {
        int wv = tid >> 6, lane = tid & 63;
        int am = lane & 15, aq = lane >> 4;
        const sh8* Bp = (const sh8*)PkU;
        float4* red = (float4*)sm;                    // [512] float4 = 8 KB
        int k0 = wv * U_KCHUNK, k1 = min(KT_S, k0 + U_KCHUNK);
        f4v acc = {0.f, 0.f, 0.f, 0.f};
        int mt, nt;
        if (bid < HV_GU_END) {
            // Gu[u1,u2] = sum_s B[u1,s]*B[u2,s]
            mt = bid / NT_U; nt = bid % NT_U;
            for (int kt = k0; kt < k1; ++kt) {
                sh8 aa = Bp[(kt * NT_U + mt) * 64 + lane];
                sh8 bb = Bp[(kt * NT_U + nt) * 64 + lane];
                acc = __builtin_amdgcn_mfma_f32_16x16x32_bf16(aa, bb, acc, 0, 0, 0);
            }
        } else {
            // yT[d,u] = sum_s Et[d,s]*B[u,s]  (hi/lo split E)
            int tile = bid - HV_GU_END;
            mt = tile / NT_U; nt = tile % NT_U;
            const unsigned short* rH = EtHi + (size_t)(mt * 16 + am) * SPAD;
            const unsigned short* rL = EtLo + (size_t)(mt * 16 + am) * SPAD;
            for (int kt = k0; kt < k1; ++kt) {
                sh8 bb = Bp[(kt * NT_U + nt) * 64 + lane];
                sh8 ah = *(const sh8*)(rH + kt * 32 + aq * 8);
                sh8 al = *(const sh8*)(rL + kt * 32 + aq * 8);
                acc = __builtin_amdgcn_mfma_f32_16x16x32_bf16(ah, bb, acc, 0, 0, 0);
                acc = __builtin_amdgcn_mfma_f32_16x16x32_bf16(al, bb, acc, 0, 0, 0);
            }
        }
        red[wv * 64 + lane] = make_float4(acc[0], acc[1], acc[2], acc[3]);
        __syncthreads();
        if (wv == 0) {
            float4 v = red[lane];
            #pragma unroll
            for (int w2 = 1; w2 < 8; ++w2) {
                float4 p = red[w2 * 64 + lane];
                v.x += p.x; v.y += p.y; v.z += p.z; v.w += p.w;
            }
            float vr[4] = {v.x, v.y, v.z, v.w};
            float* dst = (bid < HV_GU_END) ? Gu : yT;
            #pragma unroll
            for (int reg = 0; reg < 4; ++reg)
                dst[(size_t)(mt * 16 + aq * 4 + reg) * UPAD + nt * 16 + am] = vr[reg];
        }
        return;
    }
    // ---- Pc / weight-prep roles (512 threads) ----
    int rb = bid - HV_YT_END;                         // 0..8
    int isf32 = detect_f32(uE);
    if (rb == 8) {                                    // weight prep
        for (int i = tid; i < 4096; i += 512) {
            int j = i & 7, lane = (i >> 3) & 63, kh = (i >> 9) & 1, t = i >> 10;
            int k = kh * 32 + ((lane >> 4) & 3) * 8 + j;
            int n = t * 16 + (lane & 15);
            Wb[i] = f2bs(ldf(W2, k * 64 + n, isf32));
        }
        for (int i = tid; i < WF_TOT - 4096; i += 512) {
            int g = 4096 + i;
            float v;
            if      (g < WF_G1)  v = ldf(b1,  g - WF_B1,   isf32);
            else if (g < WF_BE1) v = ldf(g1,  g - WF_G1,   isf32);
            else if (g < WF_B2)  v = ldf(be1, g - WF_BE1,  isf32);
            else if (g < WF_G2)  v = ldf(b2,  g - WF_B2,   isf32);
            else if (g < WF_BE2) v = ldf(g2,  g - WF_G2,   isf32);
            else if (g < WF_W3)  v = ldf(be2, g - WF_BE2,  isf32);
            else if (g < WF_B3)  v = ldf(W3,  g - WF_W3,   isf32);
            else                 v = ldf(b3,  0,           isf32);
            Wf[g] = v;
        }
        return;
    }
    int side = rb >> 2;                               // 0 = user, 1 = service
    int j0 = (rb & 3) * 16;                           // 16 Pc-columns per block
    const void* Hy = side ? iHy : uHy;                // [32][128]
    long wbase = (long)side * D_DIM * H_DIM;
    float* Hs = sm;                                   // [32][129]
    float* Ws = sm + R_DIM * 129;                     // [128][16]
    float* Ts = Ws + D_DIM * 16;                      // [32][16]
    if (isf32) {
        const float* H = (const float*)Hy;
        for (int i = tid; i < R_DIM * D_DIM; i += 512)
            Hs[(i >> 7) * 129 + (i & 127)] = H[i];
        const float* Wp = (const float*)W1 + wbase;
        for (int i = tid; i < D_DIM * 16; i += 512)
            Ws[i] = Wp[(i >> 4) * H_DIM + j0 + (i & 15)];
    } else {
        const unsigned short* H = (const unsigned short*)Hy;
        for (int i = tid; i < R_DIM * D_DIM; i += 512)
            Hs[(i >> 7) * 129 + (i & 127)] = bu2f(H[i]);
        const unsigned short* Wp = (const unsigned short*)W1 + wbase;
        for (int i = tid; i < D_DIM * 16; i += 512)
            Ws[i] = bu2f(Wp[(i >> 4) * H_DIM + j0 + (i & 15)]);
    }
    __syncthreads();
    for (int idx = tid; idx < R_DIM * 16; idx += 512) {
        int a = idx >> 4, j = idx & 15;
        float acc = 0.f;
        #pragma unroll 8
        for (int d = 0; d < D_DIM; ++d)
            acc = fmaf(Hs[a * 129 + d], Ws[d * 16 + j], acc);
        Ts[idx] = acc;
    }
    __syncthreads();
    for (int idx = tid; idx < D_DIM * 16; idx += 512) {
        int d = idx >> 4, j = idx & 15;
        float acc = 0.f;
        #pragma unroll
        for (int a = 0; a < R_DIM; ++a)
            acc = fmaf(Hs[a * 129 + d], Ts[a * 16 + j], acc);
        Pc[side * D_DIM * H_DIM + d * H_DIM + j0 + j] = acc;
    }
}

// ---------- mid: exact fp32 tiny chains, one block per u-row; streaming loads ----------
__global__ void __launch_bounds__(256)
k_mid(const float* __restrict__ uEt, const float* __restrict__ Gu,
      const float* __restrict__ yT, const float* __restrict__ Pc,
      const float* __restrict__ Wf,
      unsigned short* __restrict__ wTH, unsigned short* __restrict__ wTL,
      float* __restrict__ A) {
    __shared__ float gr[UPAD];
    __shared__ float te[2 * D_DIM], ty[2 * D_DIM];
    int r = blockIdx.x, tid = threadIdx.x;
    for (int i = tid; i < U_CNT; i += 256) gr[i] = Gu[(size_t)r * UPAD + i];
    __syncthreads();
    {
        int d = tid & 127, h = tid >> 7;              // a-loop split in halves
        int a0 = h ? 170 : 0, a1 = h ? U_CNT : 170;
        float se = 0.f, sy = 0.f;
        const float* erow = uEt + (size_t)d * UPAD;   // contiguous stream
        const float* yrow = yT + (size_t)d * UPAD;
        #pragma unroll 4
        for (int a = a0; a < a1; ++a) {
            float g = gr[a];
            se = fmaf(g, erow[a], se);
            sy = fmaf(g, yrow[a], sy);
        }
        te[h * 128 + d] = se; ty[h * 128 + d] = sy;
    }
    __syncthreads();
    if (tid < 128) { te[tid] += te[128 + tid]; ty[tid] += ty[128 + tid]; }
    __syncthreads();
    int j = tid & 63;
    if (tid < 64) {
        float w = 0.f;
        #pragma unroll 8
        for (int d = 0; d < D_DIM; ++d)
            w = fmaf(te[d], Pc[D_DIM * H_DIM + d * H_DIM + j], w);   // Pc_i
        unsigned short hi = f2bs(w);
        unsigned short lo = f2bs(w - bu2f(hi));
        wTH[(size_t)j * UPAD + r] = hi;
        wTL[(size_t)j * UPAD + r] = lo;
    } else if (tid < 128) {
        float au = Wf[WF_B1 + j];
        #pragma unroll 8
        for (int d = 0; d < D_DIM; ++d)
            au = fmaf(ty[d], Pc[d * H_DIM + j], au);                 // Pc_u
        A[(size_t)r * H_DIM + j] = au;
    }
}

// ---------- A_s = B^T w via MFMA over PkS; LDS-transposed coalesced store ----------
__global__ void __launch_bounds__(256)
k_as(const unsigned short* __restrict__ wTH, const unsigned short* __restrict__ wTL,
     const unsigned short* __restrict__ PkS, float* __restrict__ A) {
    __shared__ float ls[16][65];
    int nt = blockIdx.x;                              // 0..364
    int tid = threadIdx.x, wv = tid >> 6, lane = tid & 63;
    int am = lane & 15, aq = lane >> 4;
    const sh8* Bp = (const sh8*)PkS;
    const unsigned short* rH = wTH + (size_t)(wv * 16 + am) * UPAD;
    const unsigned short* rL = wTL + (size_t)(wv * 16 + am) * UPAD;
    f4v acc0 = {0.f, 0.f, 0.f, 0.f}, acc1 = acc0;
    #pragma unroll
    for (int kt = 0; kt < KT_U; ++kt) {
        sh8 bb = Bp[(kt * NT_S + nt) * 64 + lane];
        sh8 ah = *(const sh8*)(rH + kt * 32 + aq * 8);
        sh8 al = *(const sh8*)(rL + kt * 32 + aq * 8);
        acc0 = __builtin_amdgcn_mfma_f32_16x16x32_bf16(ah, bb, acc0, 0, 0, 0);
        acc1 = __builtin_amdgcn_mfma_f32_16x16x32_bf16(al, bb, acc1, 0, 0, 0);
    }
    #pragma unroll
    for (int reg = 0; reg < 4; ++reg)
        ls[am][wv * 16 + aq * 4 + reg] = acc0[reg] + acc1[reg];   // [s_local][j]
    __syncthreads();
    int sl = tid >> 4, j0 = (tid & 15) * 4;
    int s = nt * 16 + sl;
    if (s < S_CNT) {
        float4 v = make_float4(ls[sl][j0], ls[sl][j0 + 1], ls[sl][j0 + 2], ls[sl][j0 + 3]);
        *(float4*)(A + (size_t)(U_CNT + s) * H_DIM + j0) = v;
    }
}

// ---------- fused MLP via MFMA: persistent + pipelined; DPP reductions ----------
// (no min-waves launch bound: R2 lesson -- it forced spills, 48 VGPR + 800MB scratch)
__global__ void __launch_bounds__(256)
HyperModel_65755949301857_kernel(
      const float* __restrict__ A, const int* __restrict__ userIdx,
      const int* __restrict__ servIdx, const float* __restrict__ Wf,
      const unsigned short* __restrict__ Wb,
      void* __restrict__ out, const void* __restrict__ uE) {
    int tid = threadIdx.x;
    int wv = tid >> 6, lane = tid & 63;
    int isf32 = detect_f32(uE);
    int m = lane & 15, quad = lane >> 4;

    const sh8* Bp = (const sh8*)Wb;
    sh8 b00 = Bp[0 * 64 + lane], b01 = Bp[1 * 64 + lane];
    sh8 b10 = Bp[2 * 64 + lane], b11 = Bp[3 * 64 + lane];
    sh8 b20 = Bp[4 * 64 + lane], b21 = Bp[5 * 64 + lane];
    sh8 b30 = Bp[6 * 64 + lane], b31 = Bp[7 * 64 + lane];
    float b2c0 = Wf[WF_B2 + m],      b2c1 = Wf[WF_B2 + 16 + m];
    float b2c2 = Wf[WF_B2 + 32 + m], b2c3 = Wf[WF_B2 + 48 + m];
    float g2c0 = Wf[WF_G2 + m],      g2c1 = Wf[WF_G2 + 16 + m];
    float g2c2 = Wf[WF_G2 + 32 + m], g2c3 = Wf[WF_G2 + 48 + m];
    float e2c0 = Wf[WF_BE2 + m],      e2c1 = Wf[WF_BE2 + 16 + m];
    float e2c2 = Wf[WF_BE2 + 32 + m], e2c3 = Wf[WF_BE2 + 48 + m];
    float w3c0 = Wf[WF_W3 + m],      w3c1 = Wf[WF_W3 + 16 + m];
    float w3c2 = Wf[WF_W3 + 32 + m], w3c3 = Wf[WF_W3 + 48 + m];
    float b3v = Wf[WF_B3];
    const float* G1l = Wf + WF_G1 + quad * 8;
    const float* BE1l = Wf + WF_BE1 + quad * 8;

    const long TILES = B_CNT / 16;                    // 31250
    const long stride = (long)gridDim.x * 4;
    long tile = (long)blockIdx.x * 4 + wv;
    if (tile >= TILES) return;

    int r0 = (int)(tile * 16 + m);
    const float4* Au = (const float4*)(A + (long)userIdx[r0] * 64);
    const float4* As = (const float4*)(A + (long)(servIdx[r0] + U_CNT) * 64);
    float4 bu0 = Au[quad * 2], bu1 = Au[quad * 2 + 1], bu2 = Au[8 + quad * 2], bu3 = Au[9 + quad * 2];
    float4 bs0 = As[quad * 2], bs1 = As[quad * 2 + 1], bs2 = As[8 + quad * 2], bs3 = As[9 + quad * 2];
    long tn = tile + stride;
    int uin = 0, sin = 0;
    if (tn < TILES) {
        int rn = (int)(tn * 16 + m);
        uin = userIdx[rn];
        sin = servIdx[rn] + U_CNT;
    }

    while (true) {
        float zl[8], zh[8];
        zl[0] = bu0.x + bs0.x; zl[1] = bu0.y + bs0.y; zl[2] = bu0.z + bs0.z; zl[3] = bu0.w + bs0.w;
        zl[4] = bu1.x + bs1.x; zl[5] = bu1.y + bs1.y; zl[6] = bu1.z + bs1.z; zl[7] = bu1.w + bs1.w;
        zh[0] = bu2.x + bs2.x; zh[1] = bu2.y + bs2.y; zh[2] = bu2.z + bs2.z; zh[3] = bu2.w + bs2.w;
        zh[4] = bu3.x + bs3.x; zh[5] = bu3.y + bs3.y; zh[6] = bu3.z + bs3.z; zh[7] = bu3.w + bs3.w;

        long tcur = tile;
        bool have_next = (tn < TILES);
        if (have_next) {
            const float4* Au2 = (const float4*)(A + (long)uin * 64);
            const float4* As2 = (const float4*)(A + (long)sin * 64);
            bu0 = Au2[quad * 2]; bu1 = Au2[quad * 2 + 1]; bu2 = Au2[8 + quad * 2]; bu3 = Au2[9 + quad * 2];
            bs0 = As2[quad * 2]; bs1 = As2[quad * 2 + 1]; bs2 = As2[8 + quad * 2]; bs3 = As2[9 + quad * 2];
            long tnn = tn + stride;
            if (tnn < TILES) {
                int rnn = (int)(tnn * 16 + m);
                uin = userIdx[rnn];
                sin = servIdx[rnn] + U_CNT;
            }
            tile = tn;
            tn = tnn;
        }

        float s = 0.f, q = 0.f;
        #pragma unroll
        for (int j = 0; j < 8; ++j) {
            s += zl[j] + zh[j];
            q = fmaf(zl[j], zl[j], q);
            q = fmaf(zh[j], zh[j], q);
        }
        s += __shfl_xor(s, 16, 64); s += __shfl_xor(s, 32, 64);
        q += __shfl_xor(q, 16, 64); q += __shfl_xor(q, 32, 64);
        float mu = s * (1.f / 64.f);
        float rs = rsqrtf(q * (1.f / 64.f) - mu * mu + LN_EPS);
        float nm = -mu * rs;

        sh8 a0, a1;
        #pragma unroll
        for (int j = 0; j < 8; ++j) {
            float h0 = fmaxf(fmaf(fmaf(zl[j], rs, nm), G1l[j],      BE1l[j]),      0.f);
            float h1 = fmaxf(fmaf(fmaf(zh[j], rs, nm), G1l[32 + j], BE1l[32 + j]), 0.f);
            a0[j] = (short)f2bs(h0);
            a1[j] = (short)f2bs(h1);
        }

        f4v acc0 = {0.f, 0.f, 0.f, 0.f}, acc1 = acc0, acc2 = acc0, acc3 = acc0;
        acc0 = __builtin_amdgcn_mfma_f32_16x16x32_bf16(a0, b00, acc0, 0, 0, 0);
        acc0 = __builtin_amdgcn_mfma_f32_16x16x32_bf16(a1, b01, acc0, 0, 0, 0);
        acc1 = __builtin_amdgcn_mfma_f32_16x16x32_bf16(a0, b10, acc1, 0, 0, 0);
        acc1 = __builtin_amdgcn_mfma_f32_16x16x32_bf16(a1, b11, acc1, 0, 0, 0);
        acc2 = __builtin_amdgcn_mfma_f32_16x16x32_bf16(a0, b20, acc2, 0, 0, 0);
        acc2 = __builtin_amdgcn_mfma_f32_16x16x32_bf16(a1, b21, acc2, 0, 0, 0);
        acc3 = __builtin_amdgcn_mfma_f32_16x16x32_bf16(a0, b30, acc3, 0, 0, 0);
        acc3 = __builtin_amdgcn_mfma_f32_16x16x32_bf16(a1, b31, acc3, 0, 0, 0);

        float y0[4], y1[4], y2[4], y3[4];
        float srow[4], qrow[4];
        #pragma unroll
        for (int reg = 0; reg < 4; ++reg) {
            y0[reg] = acc0[reg] + b2c0;
            y1[reg] = acc1[reg] + b2c1;
            y2[reg] = acc2[reg] + b2c2;
            y3[reg] = acc3[reg] + b2c3;
            srow[reg] = (y0[reg] + y1[reg]) + (y2[reg] + y3[reg]);
            float qa = y0[reg] * y0[reg];
            qa = fmaf(y1[reg], y1[reg], qa);
            qa = fmaf(y2[reg], y2[reg], qa);
            qa = fmaf(y3[reg], y3[reg], qa);
            qrow[reg] = qa;
        }
        #pragma unroll
        for (int reg = 0; reg < 4; ++reg) {           // DPP: 16-lane sums, no LDS
            srow[reg] = rowsum16(srow[reg]);
            qrow[reg] = rowsum16(qrow[reg]);
        }
        float o[4];
        #pragma unroll
        for (int reg = 0; reg < 4; ++reg) {
            float mu2 = srow[reg] * (1.f / 64.f);
            float rs2 = rsqrtf(qrow[reg] * (1.f / 64.f) - mu2 * mu2 + LN_EPS);
            float nm2 = -mu2 * rs2;
            float t0 = fmaxf(fmaf(fmaf(y0[reg], rs2, nm2), g2c0, e2c0), 0.f);
            float t1 = fmaxf(fmaf(fmaf(y1[reg], rs2, nm2), g2c1, e2c1), 0.f);
            float t2 = fmaxf(fmaf(fmaf(y2[reg], rs2, nm2), g2c2, e2c2), 0.f);
            float t3 = fmaxf(fmaf(fmaf(y3[reg], rs2, nm2), g2c3, e2c3), 0.f);
            o[reg] = fmaf(t0, w3c0, fmaf(t1, w3c1, fmaf(t2, w3c2, t3 * w3c3)));
        }
        #pragma unroll
        for (int reg = 0; reg < 4; ++reg) o[reg] = rowsum16(o[reg]);
        if (m == 0) {
            long rb = tcur * 16 + quad * 4;
            if (isf32) {
                float4 v = make_float4(o[0] + b3v, o[1] + b3v, o[2] + b3v, o[3] + b3v);
                *(float4*)((float*)out + rb) = v;
            } else {
                ushort4 v;
                v.x = f2bs(o[0] + b3v);
                v.y = f2bs(o[1] + b3v);
                v.z = f2bs(o[2] + b3v);
                v.w = f2bs(o[3] + b3v);
                *(ushort4*)((bf16*)out + rb) = v;
            }
        }
        if (!have_next) break;
    }
}

extern "C" __attribute__((visibility("default")))
void kernel_launch(void* const* d_in, const int* in_sizes, int n_in,
                   void* d_out, int out_size, void* d_ws, size_t ws_size,
                   hipStream_t stream) {
    const void* uE   = d_in[0];
    const void* iE   = d_in[1];
    const void* uHy  = d_in[2];
    const void* iHy  = d_in[3];
    const void* W1   = d_in[4];
    const void* b1   = d_in[5];
    const void* g1   = d_in[6];
    const void* be1  = d_in[7];
    const void* W2   = d_in[8];
    const void* b2   = d_in[9];
    const void* g2   = d_in[10];
    const void* be2  = d_in[11];
    const void* W3   = d_in[12];
    const void* b3   = d_in[13];
    const void* adj_vals = d_in[14];
    const int*  adj_rows = (const int*)d_in[15];
    const int*  adj_cols = (const int*)d_in[16];
    const int*  userIdx  = (const int*)d_in[17];
    const int*  servIdx  = (const int*)d_in[18];

    char* w = (char*)d_ws;
    size_t off = 0;
    auto alloc = [&](size_t bytes) -> char* {
        char* p = w + off;
        off += (bytes + 255) & ~(size_t)255;
        return p;
    };
    unsigned short* EtHi = (unsigned short*)alloc((size_t)ET_U16 * 2);
    unsigned short* EtLo = (unsigned short*)alloc((size_t)ET_U16 * 2);
    float* Gu   = (float*)alloc((size_t)UPAD * UPAD * 4);
    float* yT   = (float*)alloc((size_t)D_DIM * UPAD * 4);
    float* uEt  = (float*)alloc((size_t)D_DIM * UPAD * 4);
    float* Pc   = (float*)alloc((size_t)2 * D_DIM * H_DIM * 4);
    float* A    = (float*)alloc((size_t)N_CNT * H_DIM * 4);
    float* Wf   = (float*)alloc((size_t)WF_TOT * 4);
    unsigned short* Wb = (unsigned short*)alloc((size_t)4096 * 2);
    // zero-init span: PkS..wTL contiguous (pads must be 0 every iteration)
    unsigned short* PkS = (unsigned short*)alloc((size_t)PKS_U16 * 2);
    unsigned short* PkU = (unsigned short*)alloc((size_t)PKU_U16 * 2);
    unsigned short* wTH = (unsigned short*)alloc((size_t)WT_U16 * 2);
    unsigned short* wTL = (unsigned short*)alloc((size_t)WT_U16 * 2);
    size_t zspan = (size_t)((char*)(wTL + WT_U16) - (char*)PkS);

    hipMemsetAsync(PkS, 0, zspan, stream);
    k_pre<<<PRE_UNITS, 256, 0, stream>>>(iE, EtHi, EtLo, adj_rows, adj_cols,
                                         adj_vals, PkS, PkU, uEt, uE);
    k_heavy<<<HV_BLOCKS, 512, 0, stream>>>(EtHi, EtLo, PkU, Gu, yT,
                                           uHy, iHy, W1, W2, b1, g1, be1,
                                           b2, g2, be2, W3, b3,
                                           Pc, Wf, Wb, uE);
    k_mid<<<U_CNT, 256, 0, stream>>>(uEt, Gu, yT, Pc, Wf, wTH, wTL, A);
    k_as<<<NT_S, 256, 0, stream>>>(wTH, wTL, PkS, A);
    HyperModel_65755949301857_kernel<<<MLP_BLOCKS, 256, 0, stream>>>(
        A, userIdx, servIdx, Wf, Wb, d_out, uE);
}

// Round 6
// 181.224 us; speedup vs baseline: 2.2775x; 1.1632x over previous
//
#include <hip/hip_runtime.h>
#include <hip/hip_bf16.h>

#define U_CNT 339
#define S_CNT 5825
#define N_CNT 6164          // U + S
#define D_DIM 128
#define R_DIM 32
#define B_CNT 500000
#define NNZ_U 200000        // edges with u-row (first half of rows=concat(u,s))
#define H_DIM 64
#define LN_EPS 1e-5f

// ---- padded dims ----
#define SPAD 5856           // 183*32  (s padded to K-granularity 32)
#define UPAD 352            // 11*32   (u padded)
#define KT_S 183            // s as K: 5856/32
#define KT_U 11             // u as K: 352/32
#define NT_S 365            // s as N: 5840/16 (>= 5825)
#define NT_U 22             // u as N: 352/16
#define U_KCHUNK 23         // 8*23 = 184 >= 183 (8-way split-K)

#define ET_U16 (D_DIM * SPAD)          // s-side E^T plane (ushorts)
#define PKS_U16 (KT_U * NT_S * 512)    // B packed [k=u][n=s] MFMA B-frags
#define PKU_U16 (KT_S * NT_U * 512)    // B packed [k=s][n=u] MFMA B-frags
                                       // (also serves as GU's A-frag: same lane layout)
#define WT_U16  (H_DIM * UPAD)         // w^T [j][u] hi/lo planes
#define GU_U16  (UPAD * UPAD)          // Gu hi/lo planes, row-major
#define V_U16   (KT_U * 8 * 512)       // V = [y*Pc_u | Eu*Pc_i] as B-frags (352x128)

// k_pre units: 183 s-transpose + 11 u-transpose + 782 edge-pack
#define PRE_S_UNITS 183
#define PRE_U_UNITS 11
#define PRE_UT_END (PRE_S_UNITS + PRE_U_UNITS)            // 194
#define PRE_EDGE_UNITS ((NNZ_U + 255) / 256)              // 782
#define PRE_UNITS (PRE_UT_END + PRE_EDGE_UNITS)           // 976

// k_heavy roles: 484 GU tiles + 176 yT tiles + 9 Pc/weight blocks, 512 thr
#define HV_GU_END 484
#define HV_YT_END 660
#define HV_BLOCKS 669

// fp32 weight-block offsets (elements)
#define WF_B1   4096
#define WF_G1   4160
#define WF_BE1  4224
#define WF_B2   4288
#define WF_G2   4352
#define WF_BE2  4416
#define WF_W3   4480
#define WF_B3   4544
#define WF_TOT  4545

#define MLP_BLOCKS 1024     // measured faster than 1280 (R0 51.2us vs R4 58.6us)

typedef __hip_bfloat16 bf16;
typedef __attribute__((ext_vector_type(8))) short sh8;   // 8 bf16 (MFMA A/B frag)
typedef __attribute__((ext_vector_type(4))) float f4v;   // MFMA C/D frag

__device__ __forceinline__ float b2f(bf16 x) { return __bfloat162float(x); }
__device__ __forceinline__ unsigned short f2bs(float f) {
    union { bf16 b; unsigned short s; } u;
    u.b = __float2bfloat16(f);
    return u.s;
}
__device__ __forceinline__ float bu2f(unsigned int lo16) {   // bf16 bits -> f32
    return __uint_as_float(lo16 << 16);
}
__device__ __forceinline__ float ldf(const void* p, long i, int isf32) {
    return isf32 ? ((const float*)p)[i] : b2f(((const bf16*)p)[i]);
}
// per-wave dtype detect (no flag buffer, no extra launch); wave-uniform result
__device__ __forceinline__ int detect_f32(const void* uE) {
    const unsigned short* p = (const unsigned short*)uE;
    int lane = threadIdx.x & 63;
    unsigned short v = p[2 * lane];
    int e = (v >> 7) & 0xFF;
    unsigned long long m = __ballot(e >= 127);
    return (m != 0ull) ? 1 : 0;
}

// ---- DPP within-16-lane sum reduction (pure VALU, no LDS pipe) ----
// R4->R5 verified: replacing 48 __shfl_xor with DPP cut MLP 58.6->44.8us.
template<int CTRL>
__device__ __forceinline__ float dpp_add(float x) {
    int t = __builtin_amdgcn_update_dpp(0, __float_as_int(x), CTRL, 0xF, 0xF, false);
    return x + __int_as_float(t);
}
__device__ __forceinline__ float rowsum16(float x) {
    x = dpp_add<0xB1>(x);    // quad_perm [1,0,3,2]  (xor 1)
    x = dpp_add<0x4E>(x);    // quad_perm [2,3,0,1]  (xor 2)
    x = dpp_add<0x124>(x);   // row_ror:4
    x = dpp_add<0x128>(x);   // row_ror:8
    return x;
}

// ---------- pre: s-transpose | u-transpose (f32) | edge pack ----------
__global__ void __launch_bounds__(256)
k_pre(const void* __restrict__ iE,
      unsigned short* __restrict__ EtHi, unsigned short* __restrict__ EtLo,
      const int* __restrict__ rows, const int* __restrict__ cols,
      const void* __restrict__ vals,
      unsigned short* __restrict__ PkS, unsigned short* __restrict__ PkU,
      float* __restrict__ uEt,
      const void* __restrict__ uE) {
    __shared__ float ls[32 * 129];                    // padded: conflict-free
    int tid = threadIdx.x;
    int isf32 = detect_f32(uE);
    int unit = blockIdx.x;
    if (unit < PRE_S_UNITS) {                         // s-node transpose role
        int sg0 = unit * 32;
        int nl = tid >> 3, dbase = (tid & 7) * 16;
        int s = sg0 + nl;
        #pragma unroll
        for (int i = 0; i < 16; ++i) {
            int d = dbase + i;
            float v = (s < S_CNT) ? ldf(iE, (long)s * D_DIM + d, isf32) : 0.f;
            ls[nl * 129 + d] = v;
        }
        __syncthreads();
        int nl2 = tid & 31;
        int s2 = sg0 + nl2;
        #pragma unroll
        for (int i = 0; i < 16; ++i) {
            int d = (tid >> 5) * 16 + i;
            float v = ls[nl2 * 129 + d];
            unsigned short hi = f2bs(v);
            unsigned short lo = f2bs(v - bu2f(hi));
            EtHi[(size_t)d * SPAD + s2] = hi;
            EtLo[(size_t)d * SPAD + s2] = lo;
        }
    } else if (unit < PRE_UT_END) {                   // u-node transpose (f32 out)
        int ug0 = (unit - PRE_S_UNITS) * 32;
        int nl = tid >> 3, dbase = (tid & 7) * 16;
        int u = ug0 + nl;
        #pragma unroll
        for (int i = 0; i < 16; ++i) {
            int d = dbase + i;
            float v = (u < U_CNT) ? ldf(uE, (long)u * D_DIM + d, isf32) : 0.f;
            ls[nl * 129 + d] = v;
        }
        __syncthreads();
        int nl2 = tid & 31;
        int u2 = ug0 + nl2;
        #pragma unroll
        for (int i = 0; i < 16; ++i) {
            int d = (tid >> 5) * 16 + i;
            uEt[(size_t)d * UPAD + u2] = (u2 < UPAD) ? ls[nl2 * 129 + d] : 0.f;
        }
    } else {                                          // edge pack (u-rows only)
        int e = (unit - PRE_UT_END) * 256 + tid;
        if (e < NNZ_U) {
            int r = rows[e];
            if (r < U_CNT) {
                int u = r, s = cols[e] - U_CNT;
                unsigned short w = f2bs(ldf(vals, e, isf32));
                int kt = u >> 5, kq = (u >> 3) & 3, j = u & 7;
                int nt = s >> 4, nn = s & 15;
                PkS[((kt * NT_S + nt) * 64 + kq * 16 + nn) * 8 + j] = w;
                int kt2 = s >> 5, kq2 = (s >> 3) & 3, j2 = s & 7;
                int nt2 = u >> 4, nn2 = u & 15;
                PkU[((kt2 * NT_U + nt2) * 64 + kq2 * 16 + nn2) * 8 + j2] = w;
            }
        }
    }
}

// ---------- heavy: 512 threads, 8-way split-K per tile ----------
// bid<484: Gu tile -> hi/lo bf16 planes (row-major, feeds k_midB MFMA A-operand);
// bid<660: yT tile (fp32); bid 660..668: Pc / weight prep.
__global__ void __launch_bounds__(512)
k_heavy(const unsigned short* __restrict__ EtHi, const unsigned short* __restrict__ EtLo,
        const unsigned short* __restrict__ PkU,
        unsigned short* __restrict__ GuHi, unsigned short* __restrict__ GuLo,
        float* __restrict__ yT,
        const void* __restrict__ uHy, const void* __restrict__ iHy,
        const void* __restrict__ W1, const void* __restrict__ W2,
        const void* __restrict__ b1, const void* __restrict__ g1,
        const void* __restrict__ be1, const void* __restrict__ b2,
        const void* __restrict__ g2, const void* __restrict__ be2,
        const void* __restrict__ W3, const void* __restrict__ b3,
        float* __restrict__ Pc, float* __restrict__ Wf,
        unsigned short* __restrict__ Wb,
        const void* __restrict__ uE) {
    __shared__ __align__(16) float sm[6688];          // 26.7 KB arena
    int tid = threadIdx.x;
    int bid = blockIdx.x;
    if (bid < HV_YT_END) {
        int wv = tid >> 6, lane = tid & 63;
        int am = lane & 15, aq = lane >> 4;
        const sh8* Bp = (const sh8*)PkU;
        float4* red = (float4*)sm;                    // [512] float4 = 8 KB
        int k0 = wv * U_KCHUNK, k1 = min(KT_S, k0 + U_KCHUNK);
        f4v acc = {0.f, 0.f, 0.f, 0.f};
        int mt, nt;
        if (bid < HV_GU_END) {
            // Gu[u1,u2] = sum_s B[u1,s]*B[u2,s]  (A-frag == PkU frag (kt,mt))
            mt = bid / NT_U; nt = bid % NT_U;
            for (int kt = k0; kt < k1; ++kt) {
                sh8 aa = Bp[(kt * NT_U + mt) * 64 + lane];
                sh8 bb = Bp[(kt * NT_U + nt) * 64 + lane];
                acc = __builtin_amdgcn_mfma_f32_16x16x32_bf16(aa, bb, acc, 0, 0, 0);
            }
        } else {
            // yT[d,u] = sum_s Et[d,s]*B[u,s]  (hi/lo split E)
            int tile = bid - HV_GU_END;
            mt = tile / NT_U; nt = tile % NT_U;
            const unsigned short* rH = EtHi + (size_t)(mt * 16 + am) * SPAD;
            const unsigned short* rL = EtLo + (size_t)(mt * 16 + am) * SPAD;
            for (int kt = k0; kt < k1; ++kt) {
                sh8 bb = Bp[(kt * NT_U + nt) * 64 + lane];
                sh8 ah = *(const sh8*)(rH + kt * 32 + aq * 8);
                sh8 al = *(const sh8*)(rL + kt * 32 + aq * 8);
                acc = __builtin_amdgcn_mfma_f32_16x16x32_bf16(ah, bb, acc, 0, 0, 0);
                acc = __builtin_amdgcn_mfma_f32_16x16x32_bf16(al, bb, acc, 0, 0, 0);
            }
        }
        red[wv * 64 + lane] = make_float4(acc[0], acc[1], acc[2], acc[3]);
        __syncthreads();
        if (wv == 0) {
            float4 v = red[lane];
            #pragma unroll
            for (int w2 = 1; w2 < 8; ++w2) {
                float4 p = red[w2 * 64 + lane];
                v.x += p.x; v.y += p.y; v.z += p.z; v.w += p.w;
            }
            float vr[4] = {v.x, v.y, v.z, v.w};
            if (bid < HV_GU_END) {
                #pragma unroll
                for (int reg = 0; reg < 4; ++reg) {
                    size_t idx = (size_t)(mt * 16 + aq * 4 + reg) * UPAD + nt * 16 + am;
                    unsigned short hi = f2bs(vr[reg]);
                    GuHi[idx] = hi;
                    GuLo[idx] = f2bs(vr[reg] - bu2f(hi));
                }
            } else {
                #pragma unroll
                for (int reg = 0; reg < 4; ++reg)
                    yT[(size_t)(mt * 16 + aq * 4 + reg) * UPAD + nt * 16 + am] = vr[reg];
            }
        }
        return;
    }
    // ---- Pc / weight-prep roles (512 threads) ----
    int rb = bid - HV_YT_END;                         // 0..8
    int isf32 = detect_f32(uE);
    if (rb == 8) {                                    // weight prep
        for (int i = tid; i < 4096; i += 512) {
            int j = i & 7, lane = (i >> 3) & 63, kh = (i >> 9) & 1, t = i >> 10;
            int k = kh * 32 + ((lane >> 4) & 3) * 8 + j;
            int n = t * 16 + (lane & 15);
            Wb[i] = f2bs(ldf(W2, k * 64 + n, isf32));
        }
        for (int i = tid; i < WF_TOT - 4096; i += 512) {
            int g = 4096 + i;
            float v;
            if      (g < WF_G1)  v = ldf(b1,  g - WF_B1,   isf32);
            else if (g < WF_BE1) v = ldf(g1,  g - WF_G1,   isf32);
            else if (g < WF_B2)  v = ldf(be1, g - WF_BE1,  isf32);
            else if (g < WF_G2)  v = ldf(b2,  g - WF_B2,   isf32);
            else if (g < WF_BE2) v = ldf(g2,  g - WF_G2,   isf32);
            else if (g < WF_W3)  v = ldf(be2, g - WF_BE2,  isf32);
            else if (g < WF_B3)  v = ldf(W3,  g - WF_W3,   isf32);
            else                 v = ldf(b3,  0,           isf32);
            Wf[g] = v;
        }
        return;
    }
    int side = rb >> 2;                               // 0 = user, 1 = service
    int j0 = (rb & 3) * 16;                           // 16 Pc-columns per block
    const void* Hy = side ? iHy : uHy;                // [32][128]
    long wbase = (long)side * D_DIM * H_DIM;
    float* Hs = sm;                                   // [32][129]
    float* Ws = sm + R_DIM * 129;                     // [128][16]
    float* Ts = Ws + D_DIM * 16;                      // [32][16]
    if (isf32) {
        const float* H = (const float*)Hy;
        for (int i = tid; i < R_DIM * D_DIM; i += 512)
            Hs[(i >> 7) * 129 + (i & 127)] = H[i];
        const float* Wp = (const float*)W1 + wbase;
        for (int i = tid; i < D_DIM * 16; i += 512)
            Ws[i] = Wp[(i >> 4) * H_DIM + j0 + (i & 15)];
    } else {
        const unsigned short* H = (const unsigned short*)Hy;
        for (int i = tid; i < R_DIM * D_DIM; i += 512)
            Hs[(i >> 7) * 129 + (i & 127)] = bu2f(H[i]);
        const unsigned short* Wp = (const unsigned short*)W1 + wbase;
        for (int i = tid; i < D_DIM * 16; i += 512)
            Ws[i] = bu2f(Wp[(i >> 4) * H_DIM + j0 + (i & 15)]);
    }
    __syncthreads();
    for (int idx = tid; idx < R_DIM * 16; idx += 512) {
        int a = idx >> 4, j = idx & 15;
        float acc = 0.f;
        #pragma unroll 8
        for (int d = 0; d < D_DIM; ++d)
            acc = fmaf(Hs[a * 129 + d], Ws[d * 16 + j], acc);
        Ts[idx] = acc;
    }
    __syncthreads();
    for (int idx = tid; idx < D_DIM * 16; idx += 512) {
        int d = idx >> 4, j = idx & 15;
        float acc = 0.f;
        #pragma unroll
        for (int a = 0; a < R_DIM; ++a)
            acc = fmaf(Hs[a * 129 + d], Ts[a * 16 + j], acc);
        Pc[side * D_DIM * H_DIM + d * H_DIM + j0 + j] = acc;
    }
}

// ---------- midA: V = [y*Pc_u | Eu*Pc_i] (352x128 fp32 -> hi/lo B-frags) ----------
// R5 post-mortem: replaces k_mid's latency-bound serial chains. One output per
// thread, coalesced S-reads (lanes 0..31 = consecutive k), Pc broadcast.
__global__ void __launch_bounds__(256)
k_midA(const float* __restrict__ yT, const float* __restrict__ uEt,
       const float* __restrict__ Pc,
       unsigned short* __restrict__ VHi, unsigned short* __restrict__ VLo) {
    int bid = blockIdx.x;                             // 176 = 11 kt * 16 jg
    int kt = bid >> 4, jg = bid & 15;
    int tid = threadIdx.x;
    int kl = tid & 31, jl = tid >> 5;                 // 32 k x 8 j
    int k = kt * 32 + kl;
    int j = jg * 8 + jl;
    const float* S = (j < H_DIM) ? yT : uEt;          // y[k][d]=yT[d][k]; Eu[k][d]=uEt[d][k]
    const float* P = Pc + ((j < H_DIM) ? (size_t)j
                                       : (size_t)(D_DIM * H_DIM + j - H_DIM));
    float acc = 0.f;
    #pragma unroll 8
    for (int d = 0; d < D_DIM; ++d)
        acc = fmaf(S[(size_t)d * UPAD + k], P[(size_t)d * H_DIM], acc);
    unsigned short hi = f2bs(acc);
    unsigned short lo = f2bs(acc - bu2f(hi));
    int kq = (k >> 3) & 3, jj = k & 7;
    int nt = j >> 4, nn = j & 15;
    size_t idx = ((size_t)(kt * 8 + nt) * 64 + kq * 16 + nn) * 8 + jj;
    VHi[idx] = hi;
    VLo[idx] = lo;
}

// ---------- midB: [A_u | w] = Gu x V via MFMA (3-product hi/lo) ----------
// Gu pad rows are exactly 0 (PkU pads zeroed) -> w pad rows 0 for k_as.
__global__ void __launch_bounds__(256)
k_midB(const unsigned short* __restrict__ GuHi, const unsigned short* __restrict__ GuLo,
       const unsigned short* __restrict__ VHi, const unsigned short* __restrict__ VLo,
       const float* __restrict__ Wf, float* __restrict__ A,
       unsigned short* __restrict__ wTH, unsigned short* __restrict__ wTL) {
    int tid = threadIdx.x, wv = tid >> 6, lane = tid & 63;
    int am = lane & 15, aq = lane >> 4;
    int tile = blockIdx.x * 4 + wv;                   // 0..175
    int mt = tile >> 3, nt = tile & 7;
    const sh8* BH = (const sh8*)VHi;
    const sh8* BL = (const sh8*)VLo;
    const unsigned short* rH = GuHi + (size_t)(mt * 16 + am) * UPAD;
    const unsigned short* rL = GuLo + (size_t)(mt * 16 + am) * UPAD;
    f4v acc = {0.f, 0.f, 0.f, 0.f};
    #pragma unroll
    for (int kt = 0; kt < KT_U; ++kt) {
        sh8 bh = BH[(kt * 8 + nt) * 64 + lane];
        sh8 bl = BL[(kt * 8 + nt) * 64 + lane];
        sh8 ah = *(const sh8*)(rH + kt * 32 + aq * 8);
        sh8 al = *(const sh8*)(rL + kt * 32 + aq * 8);
        acc = __builtin_amdgcn_mfma_f32_16x16x32_bf16(ah, bh, acc, 0, 0, 0);
        acc = __builtin_amdgcn_mfma_f32_16x16x32_bf16(ah, bl, acc, 0, 0, 0);
        acc = __builtin_amdgcn_mfma_f32_16x16x32_bf16(al, bh, acc, 0, 0, 0);
    }
    if (nt < 4) {                                     // A_u columns 0..63 (+b1)
        int j = nt * 16 + am;
        float b1j = Wf[WF_B1 + j];
        #pragma unroll
        for (int reg = 0; reg < 4; ++reg) {
            int r = mt * 16 + aq * 4 + reg;
            if (r < U_CNT) A[(size_t)r * H_DIM + j] = acc[reg] + b1j;
        }
    } else {                                          // w columns -> wT hi/lo planes
        int j = nt * 16 + am - 64;
        int r0 = mt * 16 + aq * 4;
        ushort4 vh, vl;
        unsigned short h;
        h = f2bs(acc[0]); vh.x = h; vl.x = f2bs(acc[0] - bu2f(h));
        h = f2bs(acc[1]); vh.y = h; vl.y = f2bs(acc[1] - bu2f(h));
        h = f2bs(acc[2]); vh.z = h; vl.z = f2bs(acc[2] - bu2f(h));
        h = f2bs(acc[3]); vh.w = h; vl.w = f2bs(acc[3] - bu2f(h));
        *(ushort4*)(wTH + (size_t)j * UPAD + r0) = vh;
        *(ushort4*)(wTL + (size_t)j * UPAD + r0) = vl;
    }
}

// ---------- A_s = B^T w via MFMA over PkS; LDS-transposed coalesced store ----------
__global__ void __launch_bounds__(256)
k_as(const unsigned short* __restrict__ wTH, const unsigned short* __restrict__ wTL,
     const unsigned short* __restrict__ PkS, float* __restrict__ A) {
    __shared__ float ls[16][65];
    int nt = blockIdx.x;                              // 0..364
    int tid = threadIdx.x, wv = tid >> 6, lane = tid & 63;
    int am = lane & 15, aq = lane >> 4;
    const sh8* Bp = (const sh8*)PkS;
    const unsigned short* rH = wTH + (size_t)(wv * 16 + am) * UPAD;
    const unsigned short* rL = wTL + (size_t)(wv * 16 + am) * UPAD;
    f4v acc0 = {0.f, 0.f, 0.f, 0.f}, acc1 = acc0;
    #pragma unroll
    for (int kt = 0; kt < KT_U; ++kt) {
        sh8 bb = Bp[(kt * NT_S + nt) * 64 + lane];
        sh8 ah = *(const sh8*)(rH + kt * 32 + aq * 8);
        sh8 al = *(const sh8*)(rL + kt * 32 + aq * 8);
        acc0 = __builtin_amdgcn_mfma_f32_16x16x32_bf16(ah, bb, acc0, 0, 0, 0);
        acc1 = __builtin_amdgcn_mfma_f32_16x16x32_bf16(al, bb, acc1, 0, 0, 0);
    }
    #pragma unroll
    for (int reg = 0; reg < 4; ++reg)
        ls[am][wv * 16 + aq * 4 + reg] = acc0[reg] + acc1[reg];   // [s_local][j]
    __syncthreads();
    int sl = tid >> 4, j0 = (tid & 15) * 4;
    int s = nt * 16 + sl;
    if (s < S_CNT) {
        float4 v = make_float4(ls[sl][j0], ls[sl][j0 + 1], ls[sl][j0 + 2], ls[sl][j0 + 3]);
        *(float4*)(A + (size_t)(U_CNT + s) * H_DIM + j0) = v;
    }
}

// ---------- fused MLP via MFMA: persistent + pipelined; DPP reductions ----------
// (no min-waves launch bound: R2 lesson -- it forced spills, 48 VGPR + 800MB scratch)
__global__ void __launch_bounds__(256)
HyperModel_65755949301857_kernel(
      const float* __restrict__ A, const int* __restrict__ userIdx,
      const int* __restrict__ servIdx, const float* __restrict__ Wf,
      const unsigned short* __restrict__ Wb,
      void* __restrict__ out, const void* __restrict__ uE) {
    int tid = threadIdx.x;
    int wv = tid >> 6, lane = tid & 63;
    int isf32 = detect_f32(uE);
    int m = lane & 15, quad = lane >> 4;

    const sh8* Bp = (const sh8*)Wb;
    sh8 b00 = Bp[0 * 64 + lane], b01 = Bp[1 * 64 + lane];
    sh8 b10 = Bp[2 * 64 + lane], b11 = Bp[3 * 64 + lane];
    sh8 b20 = Bp[4 * 64 + lane], b21 = Bp[5 * 64 + lane];
    sh8 b30 = Bp[6 * 64 + lane], b31 = Bp[7 * 64 + lane];
    float b2c0 = Wf[WF_B2 + m],      b2c1 = Wf[WF_B2 + 16 + m];
    float b2c2 = Wf[WF_B2 + 32 + m], b2c3 = Wf[WF_B2 + 48 + m];
    float g2c0 = Wf[WF_G2 + m],      g2c1 = Wf[WF_G2 + 16 + m];
    float g2c2 = Wf[WF_G2 + 32 + m], g2c3 = Wf[WF_G2 + 48 + m];
    float e2c0 = Wf[WF_BE2 + m],      e2c1 = Wf[WF_BE2 + 16 + m];
    float e2c2 = Wf[WF_BE2 + 32 + m], e2c3 = Wf[WF_BE2 + 48 + m];
    float w3c0 = Wf[WF_W3 + m],      w3c1 = Wf[WF_W3 + 16 + m];
    float w3c2 = Wf[WF_W3 + 32 + m], w3c3 = Wf[WF_W3 + 48 + m];
    float b3v = Wf[WF_B3];
    const float* G1l = Wf + WF_G1 + quad * 8;
    const float* BE1l = Wf + WF_BE1 + quad * 8;

    const long TILES = B_CNT / 16;                    // 31250
    const long stride = (long)gridDim.x * 4;
    long tile = (long)blockIdx.x * 4 + wv;
    if (tile >= TILES) return;

    int r0 = (int)(tile * 16 + m);
    const float4* Au = (const float4*)(A + (long)userIdx[r0] * 64);
    const float4* As = (const float4*)(A + (long)(servIdx[r0] + U_CNT) * 64);
    float4 bu0 = Au[quad * 2], bu1 = Au[quad * 2 + 1], bu2 = Au[8 + quad * 2], bu3 = Au[9 + quad * 2];
    float4 bs0 = As[quad * 2], bs1 = As[quad * 2 + 1], bs2 = As[8 + quad * 2], bs3 = As[9 + quad * 2];
    long tn = tile + stride;
    int uin = 0, sin = 0;
    if (tn < TILES) {
        int rn = (int)(tn * 16 + m);
        uin = userIdx[rn];
        sin = servIdx[rn] + U_CNT;
    }

    while (true) {
        float zl[8], zh[8];
        zl[0] = bu0.x + bs0.x; zl[1] = bu0.y + bs0.y; zl[2] = bu0.z + bs0.z; zl[3] = bu0.w + bs0.w;
        zl[4] = bu1.x + bs1.x; zl[5] = bu1.y + bs1.y; zl[6] = bu1.z + bs1.z; zl[7] = bu1.w + bs1.w;
        zh[0] = bu2.x + bs2.x; zh[1] = bu2.y + bs2.y; zh[2] = bu2.z + bs2.z; zh[3] = bu2.w + bs2.w;
        zh[4] = bu3.x + bs3.x; zh[5] = bu3.y + bs3.y; zh[6] = bu3.z + bs3.z; zh[7] = bu3.w + bs3.w;

        long tcur = tile;
        bool have_next = (tn < TILES);
        if (have_next) {
            const float4* Au2 = (const float4*)(A + (long)uin * 64);
            const float4* As2 = (const float4*)(A + (long)sin * 64);
            bu0 = Au2[quad * 2]; bu1 = Au2[quad * 2 + 1]; bu2 = Au2[8 + quad * 2]; bu3 = Au2[9 + quad * 2];
            bs0 = As2[quad * 2]; bs1 = As2[quad * 2 + 1]; bs2 = As2[8 + quad * 2]; bs3 = As2[9 + quad * 2];
            long tnn = tn + stride;
            if (tnn < TILES) {
                int rnn = (int)(tnn * 16 + m);
                uin = userIdx[rnn];
                sin = servIdx[rnn] + U_CNT;
            }
            tile = tn;
            tn = tnn;
        }

        float s = 0.f, q = 0.f;
        #pragma unroll
        for (int j = 0; j < 8; ++j) {
            s += zl[j] + zh[j];
            q = fmaf(zl[j], zl[j], q);
            q = fmaf(zh[j], zh[j], q);
        }
        s += __shfl_xor(s, 16, 64); s += __shfl_xor(s, 32, 64);
        q += __shfl_xor(q, 16, 64); q += __shfl_xor(q, 32, 64);
        float mu = s * (1.f / 64.f);
        float rs = rsqrtf(q * (1.f / 64.f) - mu * mu + LN_EPS);
        float nm = -mu * rs;

        sh8 a0, a1;
        #pragma unroll
        for (int j = 0; j < 8; ++j) {
            float h0 = fmaxf(fmaf(fmaf(zl[j], rs, nm), G1l[j],      BE1l[j]),      0.f);
            float h1 = fmaxf(fmaf(fmaf(zh[j], rs, nm), G1l[32 + j], BE1l[32 + j]), 0.f);
            a0[j] = (short)f2bs(h0);
            a1[j] = (short)f2bs(h1);
        }

        f4v acc0 = {0.f, 0.f, 0.f, 0.f}, acc1 = acc0, acc2 = acc0, acc3 = acc0;
        acc0 = __builtin_amdgcn_mfma_f32_16x16x32_bf16(a0, b00, acc0, 0, 0, 0);
        acc0 = __builtin_amdgcn_mfma_f32_16x16x32_bf16(a1, b01, acc0, 0, 0, 0);
        acc1 = __builtin_amdgcn_mfma_f32_16x16x32_bf16(a0, b10, acc1, 0, 0, 0);
        acc1 = __builtin_amdgcn_mfma_f32_16x16x32_bf16(a1, b11, acc1, 0, 0, 0);
        acc2 = __builtin_amdgcn_mfma_f32_16x16x32_bf16(a0, b20, acc2, 0, 0, 0);
        acc2 = __builtin_amdgcn_mfma_f32_16x16x32_bf16(a1, b21, acc2, 0, 0, 0);
        acc3 = __builtin_amdgcn_mfma_f32_16x16x32_bf16(a0, b30, acc3, 0, 0, 0);
        acc3 = __builtin_amdgcn_mfma_f32_16x16x32_bf16(a1, b31, acc3, 0, 0, 0);

        float y0[4], y1[4], y2[4], y3[4];
        float srow[4], qrow[4];
        #pragma unroll
        for (int reg = 0; reg < 4; ++reg) {
            y0[reg] = acc0[reg] + b2c0;
            y1[reg] = acc1[reg] + b2c1;
            y2[reg] = acc2[reg] + b2c2;
            y3[reg] = acc3[reg] + b2c3;
            srow[reg] = (y0[reg] + y1[reg]) + (y2[reg] + y3[reg]);
            float qa = y0[reg] * y0[reg];
            qa = fmaf(y1[reg], y1[reg], qa);
            qa = fmaf(y2[reg], y2[reg], qa);
            qa = fmaf(y3[reg], y3[reg], qa);
            qrow[reg] = qa;
        }
        #pragma unroll
        for (int reg = 0; reg < 4; ++reg) {           // DPP: 16-lane sums, no LDS
            srow[reg] = rowsum16(srow[reg]);
            qrow[reg] = rowsum16(qrow[reg]);
        }
        float o[4];
        #pragma unroll
        for (int reg = 0; reg < 4; ++reg) {
            float mu2 = srow[reg] * (1.f / 64.f);
            float rs2 = rsqrtf(qrow[reg] * (1.f / 64.f) - mu2 * mu2 + LN_EPS);
            float nm2 = -mu2 * rs2;
            float t0 = fmaxf(fmaf(fmaf(y0[reg], rs2, nm2), g2c0, e2c0), 0.f);
            float t1 = fmaxf(fmaf(fmaf(y1[reg], rs2, nm2), g2c1, e2c1), 0.f);
            float t2 = fmaxf(fmaf(fmaf(y2[reg], rs2, nm2), g2c2, e2c2), 0.f);
            float t3 = fmaxf(fmaf(fmaf(y3[reg], rs2, nm2), g2c3, e2c3), 0.f);
            o[reg] = fmaf(t0, w3c0, fmaf(t1, w3c1, fmaf(t2, w3c2, t3 * w3c3)));
        }
        #pragma unroll
        for (int reg = 0; reg < 4; ++reg) o[reg] = rowsum16(o[reg]);
        if (m == 0) {
            long rb = tcur * 16 + quad * 4;
            if (isf32) {
                float4 v = make_float4(o[0] + b3v, o[1] + b3v, o[2] + b3v, o[3] + b3v);
                *(float4*)((float*)out + rb) = v;
            } else {
                ushort4 v;
                v.x = f2bs(o[0] + b3v);
                v.y = f2bs(o[1] + b3v);
                v.z = f2bs(o[2] + b3v);
                v.w = f2bs(o[3] + b3v);
                *(ushort4*)((bf16*)out + rb) = v;
            }
        }
        if (!have_next) break;
    }
}

extern "C" __attribute__((visibility("default")))
void kernel_launch(void* const* d_in, const int* in_sizes, int n_in,
                   void* d_out, int out_size, void* d_ws, size_t ws_size,
                   hipStream_t stream) {
    const void* uE   = d_in[0];
    const void* iE   = d_in[1];
    const void* uHy  = d_in[2];
    const void* iHy  = d_in[3];
    const void* W1   = d_in[4];
    const void* b1   = d_in[5];
    const void* g1   = d_in[6];
    const void* be1  = d_in[7];
    const void* W2   = d_in[8];
    const void* b2   = d_in[9];
    const void* g2   = d_in[10];
    const void* be2  = d_in[11];
    const void* W3   = d_in[12];
    const void* b3   = d_in[13];
    const void* adj_vals = d_in[14];
    const int*  adj_rows = (const int*)d_in[15];
    const int*  adj_cols = (const int*)d_in[16];
    const int*  userIdx  = (const int*)d_in[17];
    const int*  servIdx  = (const int*)d_in[18];

    char* w = (char*)d_ws;
    size_t off = 0;
    auto alloc = [&](size_t bytes) -> char* {
        char* p = w + off;
        off += (bytes + 255) & ~(size_t)255;
        return p;
    };
    unsigned short* EtHi = (unsigned short*)alloc((size_t)ET_U16 * 2);
    unsigned short* EtLo = (unsigned short*)alloc((size_t)ET_U16 * 2);
    unsigned short* GuHi = (unsigned short*)alloc((size_t)GU_U16 * 2);
    unsigned short* GuLo = (unsigned short*)alloc((size_t)GU_U16 * 2);
    unsigned short* VHi  = (unsigned short*)alloc((size_t)V_U16 * 2);
    unsigned short* VLo  = (unsigned short*)alloc((size_t)V_U16 * 2);
    unsigned short* wTH  = (unsigned short*)alloc((size_t)WT_U16 * 2);
    unsigned short* wTL  = (unsigned short*)alloc((size_t)WT_U16 * 2);
    float* yT   = (float*)alloc((size_t)D_DIM * UPAD * 4);
    float* uEt  = (float*)alloc((size_t)D_DIM * UPAD * 4);
    float* Pc   = (float*)alloc((size_t)2 * D_DIM * H_DIM * 4);
    float* A    = (float*)alloc((size_t)N_CNT * H_DIM * 4);
    float* Wf   = (float*)alloc((size_t)WF_TOT * 4);
    unsigned short* Wb = (unsigned short*)alloc((size_t)4096 * 2);
    // zero-init span: PkS+PkU contiguous (edge-pack pads must be 0 each run)
    unsigned short* PkS = (unsigned short*)alloc((size_t)PKS_U16 * 2);
    unsigned short* PkU = (unsigned short*)alloc((size_t)PKU_U16 * 2);
    size_t zspan = (size_t)((char*)(PkU + PKU_U16) - (char*)PkS);

    hipMemsetAsync(PkS, 0, zspan, stream);
    k_pre<<<PRE_UNITS, 256, 0, stream>>>(iE, EtHi, EtLo, adj_rows, adj_cols,
                                         adj_vals, PkS, PkU, uEt, uE);
    k_heavy<<<HV_BLOCKS, 512, 0, stream>>>(EtHi, EtLo, PkU, GuHi, GuLo, yT,
                                           uHy, iHy, W1, W2, b1, g1, be1,
                                           b2, g2, be2, W3, b3,
                                           Pc, Wf, Wb, uE);
    k_midA<<<176, 256, 0, stream>>>(yT, uEt, Pc, VHi, VLo);
    k_midB<<<44, 256, 0, stream>>>(GuHi, GuLo, VHi, VLo, Wf, A, wTH, wTL);
    k_as<<<NT_S, 256, 0, stream>>>(wTH, wTL, PkS, A);
    HyperModel_65755949301857_kernel<<<MLP_BLOCKS, 256, 0, stream>>>(
        A, userIdx, servIdx, Wf, Wb, d_out, uE);
}